// Round 16
// baseline (310.639 us; speedup 1.0000x reference)
//
#include <hip/hip_runtime.h>
#include <hip/hip_bf16.h>

#define BB 2
#define TT 1024
#define DD 512
#define HH 8
#define FF 16
#define HDIM 64
#define BT (BB*TT)   // 2048

typedef short bf16x8 __attribute__((ext_vector_type(8)));
typedef float f32x4  __attribute__((ext_vector_type(4)));
#define MFMA_BF16 __builtin_amdgcn_mfma_f32_16x16x32_bf16

__device__ __forceinline__ ushort f2b(float f) {
    uint u = __float_as_uint(f);
    uint r = (u + 0x7fffu + ((u >> 16) & 1u)) >> 16;
    return (ushort)r;
}

__device__ __forceinline__ uint pkbf2(float a, float b) {
    __hip_bfloat162 h = __float22bfloat162_rn(make_float2(a, b));
    union { __hip_bfloat162 h2; uint u; } c; c.h2 = h;
    return c.u;
}

// ---------------------------------------------------------------------------
// Grid barrier for 256 co-resident blocks.  Counter is zeroed by an on-stream
// hipMemsetAsync before every launch, so barrier k releases at the ABSOLUTE
// target 256*k.  Deadlock-free by induction: reaching barrier k requires
// 256*(k-1) prior increments, and every block eventually arrives at k.
// All-thread __threadfence on both sides = device-scope release/acquire.
// ---------------------------------------------------------------------------
__device__ __forceinline__ void gbar(unsigned long long* cnt,
                                     unsigned long long target) {
    __threadfence();                    // release: this thread's writes -> device
    __syncthreads();
    if (threadIdx.x == 0) {
        atomicAdd(cnt, 1ull);
        while (__hip_atomic_load(cnt, __ATOMIC_RELAXED,
                                 __HIP_MEMORY_SCOPE_AGENT) < target)
            __builtin_amdgcn_s_sleep(8);
    }
    __syncthreads();
    __threadfence();                    // acquire: invalidate stale cache
}

// ---------------------------------------------------------------------------
// One persistent kernel, 256 blocks x 512 threads, 4 phases / 3 barriers.
// Phase 0: cast f32 -> bf16 (X->Xb, Wq|Wk|Wv->Wb, Wo->Wob), grid-stride.
// Phase 1: QKV gemm 64x96 tiles (32x8=256), 8 waves=(2m x 2n)x2k, acc[2][3];
//          route Q,K (K pre-scaled 1/4) -> (bh,t,16); V -> Vt[bh][64][1024].
// Phase 2: attention (round-14 body), 2 LPT-paired units per block.
// Phase 3: out gemm 64x64 tiles (32x8=256), round-14 body.
// ---------------------------------------------------------------------------
__global__ __launch_bounds__(512) void fused_all(
    const float* __restrict__ X,  const float* __restrict__ Wq,
    const float* __restrict__ Wk, const float* __restrict__ Wv,
    const float* __restrict__ Wo,
    ushort* __restrict__ Xb, ushort* __restrict__ Wb, ushort* __restrict__ Wob,
    ushort* __restrict__ Qb, ushort* __restrict__ Kb, ushort* __restrict__ Vtg,
    ushort* __restrict__ Yb, float* __restrict__ Out,
    unsigned long long* __restrict__ cnt)
{
    __shared__ float smem[17664];   // 70656 B, aliased per phase

    const int bid = blockIdx.x;
    const int tid = threadIdx.x, w = tid >> 6, l = tid & 63;
    const int lr = l & 15, g = l >> 4;

    // ---------------- phase 0: cast ----------------
    {
        const int gtid = bid * 512 + tid;              // 0..131071
        for (int u = gtid; u < 425984; u += 131072) {
            const int i4 = u * 4;
            const float* src; ushort* dst;
            if (i4 < 1048576)      { src = X  + i4;             dst = Xb + i4; }
            else if (i4 < 1114112) { src = Wq + (i4 - 1048576); dst = Wb + (i4 - 1048576); }
            else if (i4 < 1179648) { src = Wk + (i4 - 1114112); dst = Wb + 65536 + (i4 - 1114112); }
            else if (i4 < 1441792) { src = Wv + (i4 - 1179648); dst = Wb + 131072 + (i4 - 1179648); }
            else                   { src = Wo + (i4 - 1441792); dst = Wob + (i4 - 1441792); }
            float4 v = *(const float4*)src;
            ushort4 o = { f2b(v.x), f2b(v.y), f2b(v.z), f2b(v.w) };
            *(ushort4*)dst = o;
        }
    }
    gbar(cnt, 256ull);

    // ---------------- phase 1: QKV gemm 64x96 ----------------
    {
        float (*sc)[64][100] = (float(*)[64][100])smem;   // [2][64][100] 51.2KB
        const int m0 = (bid & 31) * 64, n0 = (bid >> 5) * 96;
        const int kw = w >> 2, mw = w & 1, nw = (w >> 1) & 1;

        f32x4 acc[2][3] = {};
        const ushort* Ar = Xb + (size_t)(m0 + mw*32 + lr) * 512 + kw*256 + g*8;
        const ushort* Br = Wb + (size_t)(n0 + nw*48 + lr) * 512 + kw*256 + g*8;

        #pragma unroll
        for (int ks = 0; ks < 8; ++ks) {
            bf16x8 a0 = *(const bf16x8*)(Ar + ks*32);
            bf16x8 a1 = *(const bf16x8*)(Ar + (size_t)16*512 + ks*32);
            bf16x8 b0 = *(const bf16x8*)(Br + ks*32);
            bf16x8 b1 = *(const bf16x8*)(Br + (size_t)16*512 + ks*32);
            bf16x8 b2 = *(const bf16x8*)(Br + (size_t)32*512 + ks*32);
            acc[0][0] = MFMA_BF16(a0, b0, acc[0][0], 0, 0, 0);
            acc[0][1] = MFMA_BF16(a0, b1, acc[0][1], 0, 0, 0);
            acc[0][2] = MFMA_BF16(a0, b2, acc[0][2], 0, 0, 0);
            acc[1][0] = MFMA_BF16(a1, b0, acc[1][0], 0, 0, 0);
            acc[1][1] = MFMA_BF16(a1, b1, acc[1][1], 0, 0, 0);
            acc[1][2] = MFMA_BF16(a1, b2, acc[1][2], 0, 0, 0);
        }

        #pragma unroll
        for (int mb = 0; mb < 2; ++mb)
            #pragma unroll
            for (int nb = 0; nb < 3; ++nb)
                #pragma unroll
                for (int r = 0; r < 4; ++r)
                    sc[kw][mw*32 + mb*16 + g*4 + r][nw*48 + nb*16 + lr] = acc[mb][nb][r];
        __syncthreads();

        if (tid < 384) {
            const int col = tid % 96;
            const int rg4 = tid / 96;            // 0..3 -> rows rg4*16..+15
            const int cg  = n0 + col;
            const int tok0 = m0 + rg4*16;
            const int b = tok0 >> 10, tt0 = tok0 & 1023;
            float v16[16];
            #pragma unroll
            for (int j = 0; j < 16; ++j)
                v16[j] = sc[0][rg4*16 + j][col] + sc[1][rg4*16 + j][col];
            if (cg < 256) {
                const bool isQ = cg < 128;
                const int c = isQ ? cg : cg - 128;
                const int h = c >> 4, f = c & 15;
                ushort* Dst = isQ ? Qb : Kb;
                const float scale = isQ ? 1.0f : 0.25f;   // K pre-scaled 1/4
                #pragma unroll
                for (int j = 0; j < 16; ++j)
                    Dst[((size_t)(b*HH + h)*TT + tt0 + j)*FF + f] = f2b(v16[j] * scale);
            } else {
                const int c = cg - 256;
                const int h = c >> 6, vch = c & 63;
                ushort us[16];
                #pragma unroll
                for (int j = 0; j < 16; ++j) us[j] = f2b(v16[j]);
                ushort* base = Vtg + ((size_t)(b*HH + h)*64 + vch)*TT + tt0;
                *(uint4*)(base)     = *(uint4*)&us[0];
                *(uint4*)(base + 8) = *(uint4*)&us[8];
            }
        }
    }
    gbar(cnt, 512ull);

    // ---------------- phase 2: attention (2 LPT-paired units) ----------------
    {
        short (*Pl)[32][72] = (short(*)[32][72])smem;    // bf16 P [8][32][72]
        float* scf = smem;                               // epi overlay [8][32][68]
        float* scd = smem + 8*32*68;                     // epi [8][32]
        const bf16x8 zf = {0,0,0,0,0,0,0,0};
        const bf16x8 ones = {16256,16256,16256,16256,16256,16256,16256,16256};

        #pragma unroll 1
        for (int ui = 0; ui < 2; ++ui) {
            const int u = ui ? (511 - bid) : bid;
            const int qt = 31 - (u >> 4);
            const int bh = u & 15;
            const int b = bh >> 3, h = bh & 7;
            const int qend = qt*32 + 32;
            const int nkc = (qt + 2) >> 1;

            __syncthreads();   // protect LDS overlay across units

            bf16x8 qf[2];
            #pragma unroll
            for (int nb = 0; nb < 2; ++nb)
                qf[nb] = (l < 32)
                    ? *(const bf16x8*)(Qb + ((size_t)bh*TT + qt*32 + nb*16 + lr)*FF + g*8)
                    : zf;

            f32x4 o[4][2] = {};
            f32x4 dacc[2] = {};

            for (int kc = w; kc < nkc; kc += 8) {
                const bool diagc = (kc == nkc - 1);
                const int act = qend - kc*64;
                const int nmb = diagc ? (act >> 4) : 4;   // 2 or 4
                const int kb_max = nmb >> 1;

                for (int mb = 0; mb < nmb; ++mb) {
                    bf16x8 kf = (l < 32)
                        ? *(const bf16x8*)(Kb + ((size_t)bh*TT + kc*64 + mb*16 + lr)*FF + g*8)
                        : zf;
                    #pragma unroll
                    for (int nb = 0; nb < 2; ++nb) {
                        f32x4 z4 = {};
                        f32x4 s = MFMA_BF16(kf, qf[nb], z4, 0, 0, 0);
                        float pv[4];
                        if (diagc) {
                            const int qg = qt*32 + nb*16 + lr;
                            const int kg0 = kc*64 + mb*16 + g*4;
                            #pragma unroll
                            for (int r = 0; r < 4; ++r) {
                                float pp = fmaf(s[r], fmaf(s[r], 0.5f, 1.0f), 1.0f);
                                pv[r] = (kg0 + r > qg) ? 0.f : pp;
                            }
                        } else {
                            #pragma unroll
                            for (int r = 0; r < 4; ++r)
                                pv[r] = fmaf(s[r], fmaf(s[r], 0.5f, 1.0f), 1.0f);
                        }
                        uint2 pk = { pkbf2(pv[0], pv[1]), pkbf2(pv[2], pv[3]) };
                        *(uint2*)&Pl[w][nb*16 + lr][mb*16 + g*4] = pk;
                    }
                }

                for (int kb = 0; kb < kb_max; ++kb) {
                    #pragma unroll
                    for (int mv = 0; mv < 4; ++mv) {
                        bf16x8 vf = *(const bf16x8*)(Vtg +
                            ((size_t)bh*64 + mv*16 + lr)*TT + kc*64 + kb*32 + g*8);
                        #pragma unroll
                        for (int nb = 0; nb < 2; ++nb) {
                            bf16x8 pf = *(const bf16x8*)&Pl[w][nb*16 + lr][kb*32 + g*8];
                            o[mv][nb] = MFMA_BF16(vf, pf, o[mv][nb], 0, 0, 0);
                        }
                    }
                    #pragma unroll
                    for (int nb = 0; nb < 2; ++nb) {
                        bf16x8 pf = *(const bf16x8*)&Pl[w][nb*16 + lr][kb*32 + g*8];
                        dacc[nb] = MFMA_BF16(ones, pf, dacc[nb], 0, 0, 0);
                    }
                }
            }

            __syncthreads();   // waves done with Pl (scratch overlays it)

            #pragma unroll
            for (int mv = 0; mv < 4; ++mv)
                #pragma unroll
                for (int nb = 0; nb < 2; ++nb)
                    *(f32x4*)&scf[(size_t)(w*32 + nb*16 + lr)*68 + mv*16 + g*4] = o[mv][nb];
            if (g == 0) {
                scd[w*32 + lr]      = dacc[0][0];
                scd[w*32 + 16 + lr] = dacc[1][0];
            }

            __syncthreads();

            {
                const int q  = tid >> 4;           // 0..31
                const int v0 = (tid & 15) * 4;     // 0..60
                float dtot = 0.f;
                #pragma unroll
                for (int ww = 0; ww < 8; ++ww) dtot += scd[ww*32 + q];
                const float inv = 1.0f / (dtot + 1e-12f);
                float o0 = 0.f, o1 = 0.f, o2 = 0.f, o3 = 0.f;
                #pragma unroll
                for (int ww = 0; ww < 8; ++ww) {
                    const float* p = &scf[(size_t)(ww*32 + q)*68 + v0];
                    o0 += p[0]; o1 += p[1]; o2 += p[2]; o3 += p[3];
                }
                uint2 pk = { pkbf2(o0*inv, o1*inv), pkbf2(o2*inv, o3*inv) };
                *(uint2*)(Yb + ((size_t)(b*TT + qt*32 + q))*DD + h*HDIM + v0) = pk;
            }
        }
    }
    gbar(cnt, 768ull);

    // ---------------- phase 3: output projection 64x64 ----------------
    {
        float (*sc)[64][66] = (float(*)[64][66])smem;    // [2][64][66] 33.8KB
        const int m0 = (bid & 31) * 64, n0 = (bid >> 5) * 64;
        const int kw = w >> 2, mw = w & 1, nw = (w >> 1) & 1;

        f32x4 acc[2][2] = {};
        const ushort* Ar = Yb  + (size_t)(m0 + mw*32 + lr) * 512 + kw*256 + g*8;
        const ushort* Br = Wob + (size_t)(n0 + nw*32 + lr) * 512 + kw*256 + g*8;

        #pragma unroll
        for (int ks = 0; ks < 8; ++ks) {
            bf16x8 a0 = *(const bf16x8*)(Ar + ks*32);
            bf16x8 a1 = *(const bf16x8*)(Ar + (size_t)16*512 + ks*32);
            bf16x8 b0 = *(const bf16x8*)(Br + ks*32);
            bf16x8 b1 = *(const bf16x8*)(Br + (size_t)16*512 + ks*32);
            acc[0][0] = MFMA_BF16(a0, b0, acc[0][0], 0, 0, 0);
            acc[0][1] = MFMA_BF16(a0, b1, acc[0][1], 0, 0, 0);
            acc[1][0] = MFMA_BF16(a1, b0, acc[1][0], 0, 0, 0);
            acc[1][1] = MFMA_BF16(a1, b1, acc[1][1], 0, 0, 0);
        }

        #pragma unroll
        for (int mb = 0; mb < 2; ++mb)
            #pragma unroll
            for (int nb = 0; nb < 2; ++nb)
                #pragma unroll
                for (int r = 0; r < 4; ++r)
                    sc[kw][mw*32 + mb*16 + g*4 + r][nw*32 + nb*16 + lr] = acc[mb][nb][r];
        __syncthreads();

        const int vl = tid & 63, rg = tid >> 6;
        #pragma unroll
        for (int j = 0; j < 8; ++j) {
            const float v = sc[0][rg*8 + j][vl] + sc[1][rg*8 + j][vl];
            Out[(size_t)(m0 + rg*8 + j)*512 + n0 + vl] = v;
        }
    }
}

// ---------------------------------------------------------------------------
extern "C" void kernel_launch(void* const* d_in, const int* in_sizes, int n_in,
                              void* d_out, int out_size, void* d_ws, size_t ws_size,
                              hipStream_t stream) {
    const float* X  = (const float*)d_in[0];   // (2,1024,512)
    const float* Wq = (const float*)d_in[1];   // (128,512)
    const float* Wk = (const float*)d_in[2];   // (128,512)
    const float* Wv = (const float*)d_in[3];   // (512,512)
    const float* Wo = (const float*)d_in[4];   // (512,512)
    float* out = (float*)d_out;                // (2,1024,512)

    ushort* ws = (ushort*)d_ws;
    ushort* Xb  = ws;                    // 2048*512   = 1048576
    ushort* Wb  = Xb  + 1048576;         // 768*512    = 393216
    ushort* Wob = Wb  + 393216;          // 512*512    = 262144
    ushort* Qb  = Wob + 262144;          // 16*1024*16 = 262144
    ushort* Kb  = Qb  + 262144;          // 262144
    ushort* Vtg = Kb  + 262144;          // 16*64*1024 = 1048576
    ushort* Yb  = Vtg + 1048576;         // 2048*512   = 1048576
    unsigned long long* cnt = (unsigned long long*)(ws + 4325376); // 8-aligned

    // zero the barrier counter every call (graph-capture-legal, replay-safe)
    hipMemsetAsync((void*)cnt, 0, sizeof(unsigned long long), stream);

    fused_all<<<256, 512, 0, stream>>>(X, Wq, Wk, Wv, Wo,
                                       Xb, Wb, Wob, Qb, Kb, Vtg, Yb, out, cnt);
}

// Round 17
// 114.739 us; speedup vs baseline: 2.7074x; 2.7074x over previous
//
#include <hip/hip_runtime.h>
#include <hip/hip_bf16.h>

#define BB 2
#define TT 1024
#define DD 512
#define HH 8
#define FF 16
#define HDIM 64
#define BT (BB*TT)   // 2048

typedef short bf16x8 __attribute__((ext_vector_type(8)));
typedef float f32x4  __attribute__((ext_vector_type(4)));
#define MFMA_BF16 __builtin_amdgcn_mfma_f32_16x16x32_bf16

__device__ __forceinline__ ushort f2b(float f) {
    uint u = __float_as_uint(f);
    uint r = (u + 0x7fffu + ((u >> 16) & 1u)) >> 16;
    return (ushort)r;
}

__device__ __forceinline__ uint pkbf2(float a, float b) {
    __hip_bfloat162 h = __float22bfloat162_rn(make_float2(a, b));
    union { __hip_bfloat162 h2; uint u; } c; c.h2 = h;
    return c.u;
}

// ---------------------------------------------------------------------------
// Grid barrier for 256 co-resident blocks, FENCE-LIGHT version.
// Protocol proven correct in round 16 (absolute targets, pre-zeroed counter).
// Key change: agent-scope fences (which lower to cache-WIDE buffer_wbl2 /
// buffer_inv on gfx950's non-coherent XCD L2s) execute in ONE thread per
// block, not all 512 -- __syncthreads already drains each wave's stores to
// L2 (vmcnt(0) before s_barrier; L1 is write-through), so a single per-block
// writeback publishes them, and a single per-block invalidate before the
// closing s_barrier freshens all waves' subsequent reads.
// Poll = relaxed system-scope atomic load (cache-bypassing, no RMW
// contention, no per-poll cache maintenance).
// ---------------------------------------------------------------------------
__device__ __forceinline__ void gbar(unsigned long long* cnt,
                                     unsigned long long target) {
    __syncthreads();                    // all waves' stores drained to L2
    if (threadIdx.x == 0) {
        __threadfence();                // release: one wbl2 per block
        atomicAdd(cnt, 1ull);
        while (__hip_atomic_load(cnt, __ATOMIC_RELAXED,
                                 __HIP_MEMORY_SCOPE_SYSTEM) < target)
            __builtin_amdgcn_s_sleep(16);
        __threadfence();                // acquire: one inv per block
    }
    __syncthreads();                    // hold waves until invalidate done
}

// ---------------------------------------------------------------------------
// One persistent kernel, 256 blocks x 512 threads, 4 phases / 3 barriers.
// Phase bodies byte-identical to round 16 (numerically verified).
// ---------------------------------------------------------------------------
__global__ __launch_bounds__(512) void fused_all(
    const float* __restrict__ X,  const float* __restrict__ Wq,
    const float* __restrict__ Wk, const float* __restrict__ Wv,
    const float* __restrict__ Wo,
    ushort* __restrict__ Xb, ushort* __restrict__ Wb, ushort* __restrict__ Wob,
    ushort* __restrict__ Qb, ushort* __restrict__ Kb, ushort* __restrict__ Vtg,
    ushort* __restrict__ Yb, float* __restrict__ Out,
    unsigned long long* __restrict__ cnt)
{
    __shared__ float smem[17664];   // 70656 B, aliased per phase

    const int bid = blockIdx.x;
    const int tid = threadIdx.x, w = tid >> 6, l = tid & 63;
    const int lr = l & 15, g = l >> 4;

    // ---------------- phase 0: cast ----------------
    {
        const int gtid = bid * 512 + tid;              // 0..131071
        for (int u = gtid; u < 425984; u += 131072) {
            const int i4 = u * 4;
            const float* src; ushort* dst;
            if (i4 < 1048576)      { src = X  + i4;             dst = Xb + i4; }
            else if (i4 < 1114112) { src = Wq + (i4 - 1048576); dst = Wb + (i4 - 1048576); }
            else if (i4 < 1179648) { src = Wk + (i4 - 1114112); dst = Wb + 65536 + (i4 - 1114112); }
            else if (i4 < 1441792) { src = Wv + (i4 - 1179648); dst = Wb + 131072 + (i4 - 1179648); }
            else                   { src = Wo + (i4 - 1441792); dst = Wob + (i4 - 1441792); }
            float4 v = *(const float4*)src;
            ushort4 o = { f2b(v.x), f2b(v.y), f2b(v.z), f2b(v.w) };
            *(ushort4*)dst = o;
        }
    }
    gbar(cnt, 256ull);

    // ---------------- phase 1: QKV gemm 64x96 ----------------
    {
        float (*sc)[64][100] = (float(*)[64][100])smem;   // [2][64][100] 51.2KB
        const int m0 = (bid & 31) * 64, n0 = (bid >> 5) * 96;
        const int kw = w >> 2, mw = w & 1, nw = (w >> 1) & 1;

        f32x4 acc[2][3] = {};
        const ushort* Ar = Xb + (size_t)(m0 + mw*32 + lr) * 512 + kw*256 + g*8;
        const ushort* Br = Wb + (size_t)(n0 + nw*48 + lr) * 512 + kw*256 + g*8;

        #pragma unroll
        for (int ks = 0; ks < 8; ++ks) {
            bf16x8 a0 = *(const bf16x8*)(Ar + ks*32);
            bf16x8 a1 = *(const bf16x8*)(Ar + (size_t)16*512 + ks*32);
            bf16x8 b0 = *(const bf16x8*)(Br + ks*32);
            bf16x8 b1 = *(const bf16x8*)(Br + (size_t)16*512 + ks*32);
            bf16x8 b2 = *(const bf16x8*)(Br + (size_t)32*512 + ks*32);
            acc[0][0] = MFMA_BF16(a0, b0, acc[0][0], 0, 0, 0);
            acc[0][1] = MFMA_BF16(a0, b1, acc[0][1], 0, 0, 0);
            acc[0][2] = MFMA_BF16(a0, b2, acc[0][2], 0, 0, 0);
            acc[1][0] = MFMA_BF16(a1, b0, acc[1][0], 0, 0, 0);
            acc[1][1] = MFMA_BF16(a1, b1, acc[1][1], 0, 0, 0);
            acc[1][2] = MFMA_BF16(a1, b2, acc[1][2], 0, 0, 0);
        }

        #pragma unroll
        for (int mb = 0; mb < 2; ++mb)
            #pragma unroll
            for (int nb = 0; nb < 3; ++nb)
                #pragma unroll
                for (int r = 0; r < 4; ++r)
                    sc[kw][mw*32 + mb*16 + g*4 + r][nw*48 + nb*16 + lr] = acc[mb][nb][r];
        __syncthreads();

        if (tid < 384) {
            const int col = tid % 96;
            const int rg4 = tid / 96;            // 0..3 -> rows rg4*16..+15
            const int cg  = n0 + col;
            const int tok0 = (bid & 31) * 64 + rg4*16;
            const int b = tok0 >> 10, tt0 = tok0 & 1023;
            float v16[16];
            #pragma unroll
            for (int j = 0; j < 16; ++j)
                v16[j] = sc[0][rg4*16 + j][col] + sc[1][rg4*16 + j][col];
            if (cg < 256) {
                const bool isQ = cg < 128;
                const int c = isQ ? cg : cg - 128;
                const int h = c >> 4, f = c & 15;
                ushort* Dst = isQ ? Qb : Kb;
                const float scale = isQ ? 1.0f : 0.25f;   // K pre-scaled 1/4
                #pragma unroll
                for (int j = 0; j < 16; ++j)
                    Dst[((size_t)(b*HH + h)*TT + tt0 + j)*FF + f] = f2b(v16[j] * scale);
            } else {
                const int c = cg - 256;
                const int h = c >> 6, vch = c & 63;
                ushort us[16];
                #pragma unroll
                for (int j = 0; j < 16; ++j) us[j] = f2b(v16[j]);
                ushort* base = Vtg + ((size_t)(b*HH + h)*64 + vch)*TT + tt0;
                *(uint4*)(base)     = *(uint4*)&us[0];
                *(uint4*)(base + 8) = *(uint4*)&us[8];
            }
        }
    }
    gbar(cnt, 512ull);

    // ---------------- phase 2: attention (2 LPT-paired units) ----------------
    {
        short (*Pl)[32][72] = (short(*)[32][72])smem;    // bf16 P [8][32][72]
        float* scf = smem;                               // epi overlay [8][32][68]
        float* scd = smem + 8*32*68;                     // epi [8][32]
        const bf16x8 zf = {0,0,0,0,0,0,0,0};
        const bf16x8 ones = {16256,16256,16256,16256,16256,16256,16256,16256};

        #pragma unroll 1
        for (int ui = 0; ui < 2; ++ui) {
            const int u = ui ? (511 - bid) : bid;
            const int qt = 31 - (u >> 4);
            const int bh = u & 15;
            const int b = bh >> 3, h = bh & 7;
            const int qend = qt*32 + 32;
            const int nkc = (qt + 2) >> 1;

            __syncthreads();   // protect LDS overlay across units

            bf16x8 qf[2];
            #pragma unroll
            for (int nb = 0; nb < 2; ++nb)
                qf[nb] = (l < 32)
                    ? *(const bf16x8*)(Qb + ((size_t)bh*TT + qt*32 + nb*16 + lr)*FF + g*8)
                    : zf;

            f32x4 o[4][2] = {};
            f32x4 dacc[2] = {};

            for (int kc = w; kc < nkc; kc += 8) {
                const bool diagc = (kc == nkc - 1);
                const int act = qend - kc*64;
                const int nmb = diagc ? (act >> 4) : 4;   // 2 or 4
                const int kb_max = nmb >> 1;

                for (int mb = 0; mb < nmb; ++mb) {
                    bf16x8 kf = (l < 32)
                        ? *(const bf16x8*)(Kb + ((size_t)bh*TT + kc*64 + mb*16 + lr)*FF + g*8)
                        : zf;
                    #pragma unroll
                    for (int nb = 0; nb < 2; ++nb) {
                        f32x4 z4 = {};
                        f32x4 s = MFMA_BF16(kf, qf[nb], z4, 0, 0, 0);
                        float pv[4];
                        if (diagc) {
                            const int qg = qt*32 + nb*16 + lr;
                            const int kg0 = kc*64 + mb*16 + g*4;
                            #pragma unroll
                            for (int r = 0; r < 4; ++r) {
                                float pp = fmaf(s[r], fmaf(s[r], 0.5f, 1.0f), 1.0f);
                                pv[r] = (kg0 + r > qg) ? 0.f : pp;
                            }
                        } else {
                            #pragma unroll
                            for (int r = 0; r < 4; ++r)
                                pv[r] = fmaf(s[r], fmaf(s[r], 0.5f, 1.0f), 1.0f);
                        }
                        uint2 pk = { pkbf2(pv[0], pv[1]), pkbf2(pv[2], pv[3]) };
                        *(uint2*)&Pl[w][nb*16 + lr][mb*16 + g*4] = pk;
                    }
                }

                for (int kb = 0; kb < kb_max; ++kb) {
                    #pragma unroll
                    for (int mv = 0; mv < 4; ++mv) {
                        bf16x8 vf = *(const bf16x8*)(Vtg +
                            ((size_t)bh*64 + mv*16 + lr)*TT + kc*64 + kb*32 + g*8);
                        #pragma unroll
                        for (int nb = 0; nb < 2; ++nb) {
                            bf16x8 pf = *(const bf16x8*)&Pl[w][nb*16 + lr][kb*32 + g*8];
                            o[mv][nb] = MFMA_BF16(vf, pf, o[mv][nb], 0, 0, 0);
                        }
                    }
                    #pragma unroll
                    for (int nb = 0; nb < 2; ++nb) {
                        bf16x8 pf = *(const bf16x8*)&Pl[w][nb*16 + lr][kb*32 + g*8];
                        dacc[nb] = MFMA_BF16(ones, pf, dacc[nb], 0, 0, 0);
                    }
                }
            }

            __syncthreads();   // waves done with Pl (scratch overlays it)

            #pragma unroll
            for (int mv = 0; mv < 4; ++mv)
                #pragma unroll
                for (int nb = 0; nb < 2; ++nb)
                    *(f32x4*)&scf[(size_t)(w*32 + nb*16 + lr)*68 + mv*16 + g*4] = o[mv][nb];
            if (g == 0) {
                scd[w*32 + lr]      = dacc[0][0];
                scd[w*32 + 16 + lr] = dacc[1][0];
            }

            __syncthreads();

            {
                const int q  = tid >> 4;           // 0..31
                const int v0 = (tid & 15) * 4;     // 0..60
                float dtot = 0.f;
                #pragma unroll
                for (int ww = 0; ww < 8; ++ww) dtot += scd[ww*32 + q];
                const float inv = 1.0f / (dtot + 1e-12f);
                float o0 = 0.f, o1 = 0.f, o2 = 0.f, o3 = 0.f;
                #pragma unroll
                for (int ww = 0; ww < 8; ++ww) {
                    const float* p = &scf[(size_t)(ww*32 + q)*68 + v0];
                    o0 += p[0]; o1 += p[1]; o2 += p[2]; o3 += p[3];
                }
                uint2 pk = { pkbf2(o0*inv, o1*inv), pkbf2(o2*inv, o3*inv) };
                *(uint2*)(Yb + ((size_t)(b*TT + qt*32 + q))*DD + h*HDIM + v0) = pk;
            }
        }
    }
    gbar(cnt, 768ull);

    // ---------------- phase 3: output projection 64x64 ----------------
    {
        float (*sc)[64][66] = (float(*)[64][66])smem;    // [2][64][66] 33.8KB
        const int m0 = (bid & 31) * 64, n0 = (bid >> 5) * 64;
        const int kw = w >> 2, mw = w & 1, nw = (w >> 1) & 1;

        f32x4 acc[2][2] = {};
        const ushort* Ar = Yb  + (size_t)(m0 + mw*32 + lr) * 512 + kw*256 + g*8;
        const ushort* Br = Wob + (size_t)(n0 + nw*32 + lr) * 512 + kw*256 + g*8;

        #pragma unroll
        for (int ks = 0; ks < 8; ++ks) {
            bf16x8 a0 = *(const bf16x8*)(Ar + ks*32);
            bf16x8 a1 = *(const bf16x8*)(Ar + (size_t)16*512 + ks*32);
            bf16x8 b0 = *(const bf16x8*)(Br + ks*32);
            bf16x8 b1 = *(const bf16x8*)(Br + (size_t)16*512 + ks*32);
            acc[0][0] = MFMA_BF16(a0, b0, acc[0][0], 0, 0, 0);
            acc[0][1] = MFMA_BF16(a0, b1, acc[0][1], 0, 0, 0);
            acc[1][0] = MFMA_BF16(a1, b0, acc[1][0], 0, 0, 0);
            acc[1][1] = MFMA_BF16(a1, b1, acc[1][1], 0, 0, 0);
        }

        #pragma unroll
        for (int mb = 0; mb < 2; ++mb)
            #pragma unroll
            for (int nb = 0; nb < 2; ++nb)
                #pragma unroll
                for (int r = 0; r < 4; ++r)
                    sc[kw][mw*32 + mb*16 + g*4 + r][nw*32 + nb*16 + lr] = acc[mb][nb][r];
        __syncthreads();

        const int vl = tid & 63, rg = tid >> 6;
        #pragma unroll
        for (int j = 0; j < 8; ++j) {
            const float v = sc[0][rg*8 + j][vl] + sc[1][rg*8 + j][vl];
            Out[(size_t)(m0 + rg*8 + j)*512 + n0 + vl] = v;
        }
    }
}

// ---------------------------------------------------------------------------
extern "C" void kernel_launch(void* const* d_in, const int* in_sizes, int n_in,
                              void* d_out, int out_size, void* d_ws, size_t ws_size,
                              hipStream_t stream) {
    const float* X  = (const float*)d_in[0];   // (2,1024,512)
    const float* Wq = (const float*)d_in[1];   // (128,512)
    const float* Wk = (const float*)d_in[2];   // (128,512)
    const float* Wv = (const float*)d_in[3];   // (512,512)
    const float* Wo = (const float*)d_in[4];   // (512,512)
    float* out = (float*)d_out;                // (2,1024,512)

    ushort* ws = (ushort*)d_ws;
    ushort* Xb  = ws;                    // 2048*512   = 1048576
    ushort* Wb  = Xb  + 1048576;         // 768*512    = 393216
    ushort* Wob = Wb  + 393216;          // 512*512    = 262144
    ushort* Qb  = Wob + 262144;          // 16*1024*16 = 262144
    ushort* Kb  = Qb  + 262144;          // 262144
    ushort* Vtg = Kb  + 262144;          // 16*64*1024 = 1048576
    ushort* Yb  = Vtg + 1048576;         // 2048*512   = 1048576
    unsigned long long* cnt = (unsigned long long*)(ws + 4325376); // 8-aligned

    // zero the barrier counter every call (graph-capture-legal, replay-safe)
    hipMemsetAsync((void*)cnt, 0, sizeof(unsigned long long), stream);

    fused_all<<<256, 512, 0, stream>>>(X, Wq, Wk, Wv, Wo,
                                       Xb, Wb, Wob, Qb, Kb, Vtg, Yb, out, cnt);
}

// Round 18
// 82.106 us; speedup vs baseline: 3.7834x; 1.3975x over previous
//
#include <hip/hip_runtime.h>
#include <hip/hip_bf16.h>

#define BB 2
#define TT 1024
#define DD 512
#define HH 8
#define FF 16
#define HDIM 64
#define BT (BB*TT)   // 2048

typedef short bf16x8 __attribute__((ext_vector_type(8)));
typedef float f32x4  __attribute__((ext_vector_type(4)));
#define MFMA_BF16 __builtin_amdgcn_mfma_f32_16x16x32_bf16

__device__ __forceinline__ ushort f2b(float f) {
    uint u = __float_as_uint(f);
    uint r = (u + 0x7fffu + ((u >> 16) & 1u)) >> 16;
    return (ushort)r;
}

__device__ __forceinline__ uint pkbf2(float a, float b) {
    __hip_bfloat162 h = __float22bfloat162_rn(make_float2(a, b));
    union { __hip_bfloat162 h2; uint u; } c; c.h2 = h;
    return c.u;
}

// ---------------------------------------------------------------------------
// Grid barrier, PER-XCD-LEADER fencing (8 parallel cache-maintenance ops per
// barrier instead of 256 serialized ones).
// Stage 1 (arrive): inc A, poll A>=target -- every block's stores are in its
//   local L2 (syncthreads => vmcnt(0); L1 is write-through).
// Stage 2 (publish): first block per XCD (CAS on pre-zeroed slot) runs
//   __threadfence() = wbl2+inv for that XCD; leaders' fences run CONCURRENTLY
//   on the 8 L2s. Everyone incs C (leaders AFTER fencing) and polls
//   C>=target, so nobody passes until every in-use XCD published+invalidated.
// Hang-free: targets count BLOCKS (256k), never XCD coverage.
// Counters/slots zeroed by on-stream memset each call (graph-legal).
// ---------------------------------------------------------------------------
__device__ __forceinline__ uint get_xcc() {
    uint x;
    asm volatile("s_getreg_b32 %0, hwreg(HW_REG_XCC_ID)" : "=s"(x));
    return x & 7u;
}

__device__ __forceinline__ void gbar(unsigned long long* A,
                                     unsigned long long* C,
                                     uint* Lslots,
                                     unsigned long long target) {
    __syncthreads();                    // stores drained to local L2
    if (threadIdx.x == 0) {
        atomicAdd(A, 1ull);
        while (__hip_atomic_load(A, __ATOMIC_RELAXED,
                                 __HIP_MEMORY_SCOPE_SYSTEM) < target)
            __builtin_amdgcn_s_sleep(8);
        const uint xcd = get_xcc();
        if (atomicCAS(&Lslots[xcd], 0u, 1u) == 0u)
            __threadfence();            // one wbl2+inv per XCD, in parallel
        atomicAdd(C, 1ull);
        while (__hip_atomic_load(C, __ATOMIC_RELAXED,
                                 __HIP_MEMORY_SCOPE_SYSTEM) < target)
            __builtin_amdgcn_s_sleep(8);
    }
    __syncthreads();
}

// ---------------------------------------------------------------------------
// One persistent kernel, 256 blocks x 512 threads, 4 phases / 3 barriers.
// Phase bodies byte-identical to round 17 (numerically verified).
// ---------------------------------------------------------------------------
__global__ __launch_bounds__(512) void fused_all(
    const float* __restrict__ X,  const float* __restrict__ Wq,
    const float* __restrict__ Wk, const float* __restrict__ Wv,
    const float* __restrict__ Wo,
    ushort* __restrict__ Xb, ushort* __restrict__ Wb, ushort* __restrict__ Wob,
    ushort* __restrict__ Qb, ushort* __restrict__ Kb, ushort* __restrict__ Vtg,
    ushort* __restrict__ Yb, float* __restrict__ Out,
    unsigned long long* __restrict__ cnt)
{
    __shared__ float smem[17664];   // 70656 B, aliased per phase

    unsigned long long* A = cnt;
    unsigned long long* C = cnt + 1;
    uint* Lbase = (uint*)(cnt + 2);     // 3 barriers x 8 XCD slots

    const int bid = blockIdx.x;
    const int tid = threadIdx.x, w = tid >> 6, l = tid & 63;
    const int lr = l & 15, g = l >> 4;

    // ---------------- phase 0: cast ----------------
    {
        const int gtid = bid * 512 + tid;              // 0..131071
        for (int u = gtid; u < 425984; u += 131072) {
            const int i4 = u * 4;
            const float* src; ushort* dst;
            if (i4 < 1048576)      { src = X  + i4;             dst = Xb + i4; }
            else if (i4 < 1114112) { src = Wq + (i4 - 1048576); dst = Wb + (i4 - 1048576); }
            else if (i4 < 1179648) { src = Wk + (i4 - 1114112); dst = Wb + 65536 + (i4 - 1114112); }
            else if (i4 < 1441792) { src = Wv + (i4 - 1179648); dst = Wb + 131072 + (i4 - 1179648); }
            else                   { src = Wo + (i4 - 1441792); dst = Wob + (i4 - 1441792); }
            float4 v = *(const float4*)src;
            ushort4 o = { f2b(v.x), f2b(v.y), f2b(v.z), f2b(v.w) };
            *(ushort4*)dst = o;
        }
    }
    gbar(A, C, Lbase + 0, 256ull);

    // ---------------- phase 1: QKV gemm 64x96 ----------------
    {
        float (*sc)[64][100] = (float(*)[64][100])smem;   // [2][64][100] 51.2KB
        const int m0 = (bid & 31) * 64, n0 = (bid >> 5) * 96;
        const int kw = w >> 2, mw = w & 1, nw = (w >> 1) & 1;

        f32x4 acc[2][3] = {};
        const ushort* Ar = Xb + (size_t)(m0 + mw*32 + lr) * 512 + kw*256 + g*8;
        const ushort* Br = Wb + (size_t)(n0 + nw*48 + lr) * 512 + kw*256 + g*8;

        #pragma unroll
        for (int ks = 0; ks < 8; ++ks) {
            bf16x8 a0 = *(const bf16x8*)(Ar + ks*32);
            bf16x8 a1 = *(const bf16x8*)(Ar + (size_t)16*512 + ks*32);
            bf16x8 b0 = *(const bf16x8*)(Br + ks*32);
            bf16x8 b1 = *(const bf16x8*)(Br + (size_t)16*512 + ks*32);
            bf16x8 b2 = *(const bf16x8*)(Br + (size_t)32*512 + ks*32);
            acc[0][0] = MFMA_BF16(a0, b0, acc[0][0], 0, 0, 0);
            acc[0][1] = MFMA_BF16(a0, b1, acc[0][1], 0, 0, 0);
            acc[0][2] = MFMA_BF16(a0, b2, acc[0][2], 0, 0, 0);
            acc[1][0] = MFMA_BF16(a1, b0, acc[1][0], 0, 0, 0);
            acc[1][1] = MFMA_BF16(a1, b1, acc[1][1], 0, 0, 0);
            acc[1][2] = MFMA_BF16(a1, b2, acc[1][2], 0, 0, 0);
        }

        #pragma unroll
        for (int mb = 0; mb < 2; ++mb)
            #pragma unroll
            for (int nb = 0; nb < 3; ++nb)
                #pragma unroll
                for (int r = 0; r < 4; ++r)
                    sc[kw][mw*32 + mb*16 + g*4 + r][nw*48 + nb*16 + lr] = acc[mb][nb][r];
        __syncthreads();

        if (tid < 384) {
            const int col = tid % 96;
            const int rg4 = tid / 96;            // 0..3 -> rows rg4*16..+15
            const int cg  = n0 + col;
            const int tok0 = (bid & 31) * 64 + rg4*16;
            const int b = tok0 >> 10, tt0 = tok0 & 1023;
            float v16[16];
            #pragma unroll
            for (int j = 0; j < 16; ++j)
                v16[j] = sc[0][rg4*16 + j][col] + sc[1][rg4*16 + j][col];
            if (cg < 256) {
                const bool isQ = cg < 128;
                const int c = isQ ? cg : cg - 128;
                const int h = c >> 4, f = c & 15;
                ushort* Dst = isQ ? Qb : Kb;
                const float scale = isQ ? 1.0f : 0.25f;   // K pre-scaled 1/4
                #pragma unroll
                for (int j = 0; j < 16; ++j)
                    Dst[((size_t)(b*HH + h)*TT + tt0 + j)*FF + f] = f2b(v16[j] * scale);
            } else {
                const int c = cg - 256;
                const int h = c >> 6, vch = c & 63;
                ushort us[16];
                #pragma unroll
                for (int j = 0; j < 16; ++j) us[j] = f2b(v16[j]);
                ushort* base = Vtg + ((size_t)(b*HH + h)*64 + vch)*TT + tt0;
                *(uint4*)(base)     = *(uint4*)&us[0];
                *(uint4*)(base + 8) = *(uint4*)&us[8];
            }
        }
    }
    gbar(A, C, Lbase + 8, 512ull);

    // ---------------- phase 2: attention (2 LPT-paired units) ----------------
    {
        short (*Pl)[32][72] = (short(*)[32][72])smem;    // bf16 P [8][32][72]
        float* scf = smem;                               // epi overlay [8][32][68]
        float* scd = smem + 8*32*68;                     // epi [8][32]
        const bf16x8 zf = {0,0,0,0,0,0,0,0};
        const bf16x8 ones = {16256,16256,16256,16256,16256,16256,16256,16256};

        #pragma unroll 1
        for (int ui = 0; ui < 2; ++ui) {
            const int u = ui ? (511 - bid) : bid;
            const int qt = 31 - (u >> 4);
            const int bh = u & 15;
            const int b = bh >> 3, h = bh & 7;
            const int qend = qt*32 + 32;
            const int nkc = (qt + 2) >> 1;

            __syncthreads();   // protect LDS overlay across units

            bf16x8 qf[2];
            #pragma unroll
            for (int nb = 0; nb < 2; ++nb)
                qf[nb] = (l < 32)
                    ? *(const bf16x8*)(Qb + ((size_t)bh*TT + qt*32 + nb*16 + lr)*FF + g*8)
                    : zf;

            f32x4 o[4][2] = {};
            f32x4 dacc[2] = {};

            for (int kc = w; kc < nkc; kc += 8) {
                const bool diagc = (kc == nkc - 1);
                const int act = qend - kc*64;
                const int nmb = diagc ? (act >> 4) : 4;   // 2 or 4
                const int kb_max = nmb >> 1;

                for (int mb = 0; mb < nmb; ++mb) {
                    bf16x8 kf = (l < 32)
                        ? *(const bf16x8*)(Kb + ((size_t)bh*TT + kc*64 + mb*16 + lr)*FF + g*8)
                        : zf;
                    #pragma unroll
                    for (int nb = 0; nb < 2; ++nb) {
                        f32x4 z4 = {};
                        f32x4 s = MFMA_BF16(kf, qf[nb], z4, 0, 0, 0);
                        float pv[4];
                        if (diagc) {
                            const int qg = qt*32 + nb*16 + lr;
                            const int kg0 = kc*64 + mb*16 + g*4;
                            #pragma unroll
                            for (int r = 0; r < 4; ++r) {
                                float pp = fmaf(s[r], fmaf(s[r], 0.5f, 1.0f), 1.0f);
                                pv[r] = (kg0 + r > qg) ? 0.f : pp;
                            }
                        } else {
                            #pragma unroll
                            for (int r = 0; r < 4; ++r)
                                pv[r] = fmaf(s[r], fmaf(s[r], 0.5f, 1.0f), 1.0f);
                        }
                        uint2 pk = { pkbf2(pv[0], pv[1]), pkbf2(pv[2], pv[3]) };
                        *(uint2*)&Pl[w][nb*16 + lr][mb*16 + g*4] = pk;
                    }
                }

                for (int kb = 0; kb < kb_max; ++kb) {
                    #pragma unroll
                    for (int mv = 0; mv < 4; ++mv) {
                        bf16x8 vf = *(const bf16x8*)(Vtg +
                            ((size_t)bh*64 + mv*16 + lr)*TT + kc*64 + kb*32 + g*8);
                        #pragma unroll
                        for (int nb = 0; nb < 2; ++nb) {
                            bf16x8 pf = *(const bf16x8*)&Pl[w][nb*16 + lr][kb*32 + g*8];
                            o[mv][nb] = MFMA_BF16(vf, pf, o[mv][nb], 0, 0, 0);
                        }
                    }
                    #pragma unroll
                    for (int nb = 0; nb < 2; ++nb) {
                        bf16x8 pf = *(const bf16x8*)&Pl[w][nb*16 + lr][kb*32 + g*8];
                        dacc[nb] = MFMA_BF16(ones, pf, dacc[nb], 0, 0, 0);
                    }
                }
            }

            __syncthreads();   // waves done with Pl (scratch overlays it)

            #pragma unroll
            for (int mv = 0; mv < 4; ++mv)
                #pragma unroll
                for (int nb = 0; nb < 2; ++nb)
                    *(f32x4*)&scf[(size_t)(w*32 + nb*16 + lr)*68 + mv*16 + g*4] = o[mv][nb];
            if (g == 0) {
                scd[w*32 + lr]      = dacc[0][0];
                scd[w*32 + 16 + lr] = dacc[1][0];
            }

            __syncthreads();

            {
                const int q  = tid >> 4;           // 0..31
                const int v0 = (tid & 15) * 4;     // 0..60
                float dtot = 0.f;
                #pragma unroll
                for (int ww = 0; ww < 8; ++ww) dtot += scd[ww*32 + q];
                const float inv = 1.0f / (dtot + 1e-12f);
                float o0 = 0.f, o1 = 0.f, o2 = 0.f, o3 = 0.f;
                #pragma unroll
                for (int ww = 0; ww < 8; ++ww) {
                    const float* p = &scf[(size_t)(ww*32 + q)*68 + v0];
                    o0 += p[0]; o1 += p[1]; o2 += p[2]; o3 += p[3];
                }
                uint2 pk = { pkbf2(o0*inv, o1*inv), pkbf2(o2*inv, o3*inv) };
                *(uint2*)(Yb + ((size_t)(b*TT + qt*32 + q))*DD + h*HDIM + v0) = pk;
            }
        }
    }
    gbar(A, C, Lbase + 16, 768ull);

    // ---------------- phase 3: output projection 64x64 ----------------
    {
        float (*sc)[64][66] = (float(*)[64][66])smem;    // [2][64][66] 33.8KB
        const int m0 = (bid & 31) * 64, n0 = (bid >> 5) * 64;
        const int kw = w >> 2, mw = w & 1, nw = (w >> 1) & 1;

        f32x4 acc[2][2] = {};
        const ushort* Ar = Yb  + (size_t)(m0 + mw*32 + lr) * 512 + kw*256 + g*8;
        const ushort* Br = Wob + (size_t)(n0 + nw*32 + lr) * 512 + kw*256 + g*8;

        #pragma unroll
        for (int ks = 0; ks < 8; ++ks) {
            bf16x8 a0 = *(const bf16x8*)(Ar + ks*32);
            bf16x8 a1 = *(const bf16x8*)(Ar + (size_t)16*512 + ks*32);
            bf16x8 b0 = *(const bf16x8*)(Br + ks*32);
            bf16x8 b1 = *(const bf16x8*)(Br + (size_t)16*512 + ks*32);
            acc[0][0] = MFMA_BF16(a0, b0, acc[0][0], 0, 0, 0);
            acc[0][1] = MFMA_BF16(a0, b1, acc[0][1], 0, 0, 0);
            acc[1][0] = MFMA_BF16(a1, b0, acc[1][0], 0, 0, 0);
            acc[1][1] = MFMA_BF16(a1, b1, acc[1][1], 0, 0, 0);
        }

        #pragma unroll
        for (int mb = 0; mb < 2; ++mb)
            #pragma unroll
            for (int nb = 0; nb < 2; ++nb)
                #pragma unroll
                for (int r = 0; r < 4; ++r)
                    sc[kw][mw*32 + mb*16 + g*4 + r][nw*32 + nb*16 + lr] = acc[mb][nb][r];
        __syncthreads();

        const int vl = tid & 63, rg = tid >> 6;
        #pragma unroll
        for (int j = 0; j < 8; ++j) {
            const float v = sc[0][rg*8 + j][vl] + sc[1][rg*8 + j][vl];
            Out[(size_t)(m0 + rg*8 + j)*512 + n0 + vl] = v;
        }
    }
}

// ---------------------------------------------------------------------------
extern "C" void kernel_launch(void* const* d_in, const int* in_sizes, int n_in,
                              void* d_out, int out_size, void* d_ws, size_t ws_size,
                              hipStream_t stream) {
    const float* X  = (const float*)d_in[0];   // (2,1024,512)
    const float* Wq = (const float*)d_in[1];   // (128,512)
    const float* Wk = (const float*)d_in[2];   // (128,512)
    const float* Wv = (const float*)d_in[3];   // (512,512)
    const float* Wo = (const float*)d_in[4];   // (512,512)
    float* out = (float*)d_out;                // (2,1024,512)

    ushort* ws = (ushort*)d_ws;
    ushort* Xb  = ws;                    // 2048*512   = 1048576
    ushort* Wb  = Xb  + 1048576;         // 768*512    = 393216
    ushort* Wob = Wb  + 393216;          // 512*512    = 262144
    ushort* Qb  = Wob + 262144;          // 16*1024*16 = 262144
    ushort* Kb  = Qb  + 262144;          // 262144
    ushort* Vtg = Kb  + 262144;          // 16*64*1024 = 1048576
    ushort* Yb  = Vtg + 1048576;         // 2048*512   = 1048576
    unsigned long long* cnt = (unsigned long long*)(ws + 4325376); // 8-aligned
    // layout: A(8B) | C(8B) | L[3][8] u32 (96B) = 112 bytes

    // zero barrier counters + leader slots every call (graph-legal, replay-safe)
    hipMemsetAsync((void*)cnt, 0, 112, stream);

    fused_all<<<256, 512, 0, stream>>>(X, Wq, Wk, Wv, Wo,
                                       Xb, Wb, Wob, Qb, Kb, Vtg, Yb, out, cnt);
}

// Round 19
// 66.944 us; speedup vs baseline: 4.6403x; 1.2265x over previous
//
#include <hip/hip_runtime.h>
#include <hip/hip_bf16.h>

#define BB 2
#define TT 1024
#define DD 512
#define HH 8
#define FF 16
#define HDIM 64
#define BT (BB*TT)   // 2048

typedef short bf16x8 __attribute__((ext_vector_type(8)));
typedef float f32x4  __attribute__((ext_vector_type(4)));
#define MFMA_BF16 __builtin_amdgcn_mfma_f32_16x16x32_bf16

__device__ __forceinline__ ushort f2b(float f) {
    uint u = __float_as_uint(f);
    uint r = (u + 0x7fffu + ((u >> 16) & 1u)) >> 16;
    return (ushort)r;
}

__device__ __forceinline__ uint pkbf2(float a, float b) {
    __hip_bfloat162 h = __float22bfloat162_rn(make_float2(a, b));
    union { __hip_bfloat162 h2; uint u; } c; c.h2 = h;
    return c.u;
}

__device__ __forceinline__ uint get_xcc() {
    uint x;
    asm volatile("s_getreg_b32 %0, hwreg(HW_REG_XCC_ID)" : "=s"(x));
    return x & 7u;
}

// ---------------------------------------------------------------------------
// Hierarchical grid barrier (distribution-agnostic, hang-free).
// Memory (all zeroed per call):
//   B[0]      = A   : global arrive counter (blocks)
//   B[1..3]   = F_k : per-barrier fence-done counters
//   B[4]      = NX  : number of populated XCDs (computed in phase 0)
//   B[8+8x]   = R[x]: per-XCD release epoch, 64B-padded (<=32 pollers each)
//   S[0..7]   = X0 slots (phase-0 XCD census)
//   S[8+(k-1)*8+x] = per-barrier per-XCD winner slots
// Protocol at barrier k: all inc A; per-XCD CAS winner polls A>=256k (8
// pollers), reads NX (final: every block's census CAS+inc completed before
// its A-inc), __threadfence (8 parallel wbl2+inv), incs F_k, polls F_k>=NX,
// sets R[x]=k; everyone else polls only R[own-XCD]>=k.
// A-target counts BLOCKS, F-target counts ACTUAL populated XCDs => no
// assumption about block->XCD distribution; cannot deadlock.
// ---------------------------------------------------------------------------
__device__ __forceinline__ void gbar(unsigned long long* B, uint* S,
                                     int k, uint xcd) {
    __syncthreads();                    // stores drained to local L2
    if (threadIdx.x == 0) {
        atomicAdd(&B[0], 1ull);         // arrive (same-line RMWs pipeline)
        if (atomicCAS(&S[8 + (k - 1) * 8 + xcd], 0u, 1u) == 0u) {
            const unsigned long long tA = 256ull * (unsigned long long)k;
            while (__hip_atomic_load(&B[0], __ATOMIC_RELAXED,
                                     __HIP_MEMORY_SCOPE_SYSTEM) < tA)
                __builtin_amdgcn_s_sleep(2);
            const unsigned long long NX =
                __hip_atomic_load(&B[4], __ATOMIC_RELAXED,
                                  __HIP_MEMORY_SCOPE_SYSTEM);
            __threadfence();            // one wbl2+inv per XCD, in parallel
            atomicAdd(&B[k], 1ull);
            while (__hip_atomic_load(&B[k], __ATOMIC_RELAXED,
                                     __HIP_MEMORY_SCOPE_SYSTEM) < NX)
                __builtin_amdgcn_s_sleep(2);
            __hip_atomic_store(&B[8 + (size_t)xcd * 8],
                               (unsigned long long)k,
                               __ATOMIC_RELAXED, __HIP_MEMORY_SCOPE_SYSTEM);
        }
        while (__hip_atomic_load(&B[8 + (size_t)xcd * 8], __ATOMIC_RELAXED,
                                 __HIP_MEMORY_SCOPE_SYSTEM)
               < (unsigned long long)k)
            __builtin_amdgcn_s_sleep(2);
    }
    __syncthreads();
}

// ---------------------------------------------------------------------------
// One persistent kernel, 256 blocks x 512 threads, 4 phases / 3 barriers.
// Phase bodies byte-identical to round 18 (numerically verified).
// ---------------------------------------------------------------------------
__global__ __launch_bounds__(512) void fused_all(
    const float* __restrict__ X,  const float* __restrict__ Wq,
    const float* __restrict__ Wk, const float* __restrict__ Wv,
    const float* __restrict__ Wo,
    ushort* __restrict__ Xb, ushort* __restrict__ Wb, ushort* __restrict__ Wob,
    ushort* __restrict__ Qb, ushort* __restrict__ Kb, ushort* __restrict__ Vtg,
    ushort* __restrict__ Yb, float* __restrict__ Out,
    unsigned long long* __restrict__ Bar)
{
    __shared__ float smem[17664];   // 70656 B, aliased per phase

    unsigned long long* B = Bar;
    uint* S = (uint*)(Bar + 72);

    const int bid = blockIdx.x;
    const int tid = threadIdx.x, w = tid >> 6, l = tid & 63;
    const int lr = l & 15, g = l >> 4;
    const uint xcd = get_xcc();

    // phase-0 preamble: XCD census (NX final before any barrier-1 winner
    // reads it -- the asm use forces the NX-inc to complete before this
    // thread's later A-inc is issued).
    if (tid == 0) {
        if (atomicCAS(&S[xcd], 0u, 1u) == 0u) {
            unsigned long long r = atomicAdd(&B[4], 1ull);
            asm volatile("" :: "v"((uint)r));
        }
    }

    // ---------------- phase 0: cast ----------------
    {
        const int gtid = bid * 512 + tid;              // 0..131071
        for (int u = gtid; u < 425984; u += 131072) {
            const int i4 = u * 4;
            const float* src; ushort* dst;
            if (i4 < 1048576)      { src = X  + i4;             dst = Xb + i4; }
            else if (i4 < 1114112) { src = Wq + (i4 - 1048576); dst = Wb + (i4 - 1048576); }
            else if (i4 < 1179648) { src = Wk + (i4 - 1114112); dst = Wb + 65536 + (i4 - 1114112); }
            else if (i4 < 1441792) { src = Wv + (i4 - 1179648); dst = Wb + 131072 + (i4 - 1179648); }
            else                   { src = Wo + (i4 - 1441792); dst = Wob + (i4 - 1441792); }
            float4 v = *(const float4*)src;
            ushort4 o = { f2b(v.x), f2b(v.y), f2b(v.z), f2b(v.w) };
            *(ushort4*)dst = o;
        }
    }
    gbar(B, S, 1, xcd);

    // ---------------- phase 1: QKV gemm 64x96 ----------------
    {
        float (*sc)[64][100] = (float(*)[64][100])smem;   // [2][64][100] 51.2KB
        const int m0 = (bid & 31) * 64, n0 = (bid >> 5) * 96;
        const int kw = w >> 2, mw = w & 1, nw = (w >> 1) & 1;

        f32x4 acc[2][3] = {};
        const ushort* Ar = Xb + (size_t)(m0 + mw*32 + lr) * 512 + kw*256 + g*8;
        const ushort* Br = Wb + (size_t)(n0 + nw*48 + lr) * 512 + kw*256 + g*8;

        #pragma unroll
        for (int ks = 0; ks < 8; ++ks) {
            bf16x8 a0 = *(const bf16x8*)(Ar + ks*32);
            bf16x8 a1 = *(const bf16x8*)(Ar + (size_t)16*512 + ks*32);
            bf16x8 b0 = *(const bf16x8*)(Br + ks*32);
            bf16x8 b1 = *(const bf16x8*)(Br + (size_t)16*512 + ks*32);
            bf16x8 b2 = *(const bf16x8*)(Br + (size_t)32*512 + ks*32);
            acc[0][0] = MFMA_BF16(a0, b0, acc[0][0], 0, 0, 0);
            acc[0][1] = MFMA_BF16(a0, b1, acc[0][1], 0, 0, 0);
            acc[0][2] = MFMA_BF16(a0, b2, acc[0][2], 0, 0, 0);
            acc[1][0] = MFMA_BF16(a1, b0, acc[1][0], 0, 0, 0);
            acc[1][1] = MFMA_BF16(a1, b1, acc[1][1], 0, 0, 0);
            acc[1][2] = MFMA_BF16(a1, b2, acc[1][2], 0, 0, 0);
        }

        #pragma unroll
        for (int mb = 0; mb < 2; ++mb)
            #pragma unroll
            for (int nb = 0; nb < 3; ++nb)
                #pragma unroll
                for (int r = 0; r < 4; ++r)
                    sc[kw][mw*32 + mb*16 + g*4 + r][nw*48 + nb*16 + lr] = acc[mb][nb][r];
        __syncthreads();

        if (tid < 384) {
            const int col = tid % 96;
            const int rg4 = tid / 96;            // 0..3 -> rows rg4*16..+15
            const int cg  = n0 + col;
            const int tok0 = (bid & 31) * 64 + rg4*16;
            const int b = tok0 >> 10, tt0 = tok0 & 1023;
            float v16[16];
            #pragma unroll
            for (int j = 0; j < 16; ++j)
                v16[j] = sc[0][rg4*16 + j][col] + sc[1][rg4*16 + j][col];
            if (cg < 256) {
                const bool isQ = cg < 128;
                const int c = isQ ? cg : cg - 128;
                const int h = c >> 4, f = c & 15;
                ushort* Dst = isQ ? Qb : Kb;
                const float scale = isQ ? 1.0f : 0.25f;   // K pre-scaled 1/4
                #pragma unroll
                for (int j = 0; j < 16; ++j)
                    Dst[((size_t)(b*HH + h)*TT + tt0 + j)*FF + f] = f2b(v16[j] * scale);
            } else {
                const int c = cg - 256;
                const int h = c >> 6, vch = c & 63;
                ushort us[16];
                #pragma unroll
                for (int j = 0; j < 16; ++j) us[j] = f2b(v16[j]);
                ushort* base = Vtg + ((size_t)(b*HH + h)*64 + vch)*TT + tt0;
                *(uint4*)(base)     = *(uint4*)&us[0];
                *(uint4*)(base + 8) = *(uint4*)&us[8];
            }
        }
    }
    gbar(B, S, 2, xcd);

    // ---------------- phase 2: attention (2 LPT-paired units) ----------------
    {
        short (*Pl)[32][72] = (short(*)[32][72])smem;    // bf16 P [8][32][72]
        float* scf = smem;                               // epi overlay [8][32][68]
        float* scd = smem + 8*32*68;                     // epi [8][32]
        const bf16x8 zf = {0,0,0,0,0,0,0,0};
        const bf16x8 ones = {16256,16256,16256,16256,16256,16256,16256,16256};

        #pragma unroll 1
        for (int ui = 0; ui < 2; ++ui) {
            const int u = ui ? (511 - bid) : bid;
            const int qt = 31 - (u >> 4);
            const int bh = u & 15;
            const int b = bh >> 3, h = bh & 7;
            const int qend = qt*32 + 32;
            const int nkc = (qt + 2) >> 1;

            __syncthreads();   // protect LDS overlay across units

            bf16x8 qf[2];
            #pragma unroll
            for (int nb = 0; nb < 2; ++nb)
                qf[nb] = (l < 32)
                    ? *(const bf16x8*)(Qb + ((size_t)bh*TT + qt*32 + nb*16 + lr)*FF + g*8)
                    : zf;

            f32x4 o[4][2] = {};
            f32x4 dacc[2] = {};

            for (int kc = w; kc < nkc; kc += 8) {
                const bool diagc = (kc == nkc - 1);
                const int act = qend - kc*64;
                const int nmb = diagc ? (act >> 4) : 4;   // 2 or 4
                const int kb_max = nmb >> 1;

                for (int mb = 0; mb < nmb; ++mb) {
                    bf16x8 kf = (l < 32)
                        ? *(const bf16x8*)(Kb + ((size_t)bh*TT + kc*64 + mb*16 + lr)*FF + g*8)
                        : zf;
                    #pragma unroll
                    for (int nb = 0; nb < 2; ++nb) {
                        f32x4 z4 = {};
                        f32x4 s = MFMA_BF16(kf, qf[nb], z4, 0, 0, 0);
                        float pv[4];
                        if (diagc) {
                            const int qg = qt*32 + nb*16 + lr;
                            const int kg0 = kc*64 + mb*16 + g*4;
                            #pragma unroll
                            for (int r = 0; r < 4; ++r) {
                                float pp = fmaf(s[r], fmaf(s[r], 0.5f, 1.0f), 1.0f);
                                pv[r] = (kg0 + r > qg) ? 0.f : pp;
                            }
                        } else {
                            #pragma unroll
                            for (int r = 0; r < 4; ++r)
                                pv[r] = fmaf(s[r], fmaf(s[r], 0.5f, 1.0f), 1.0f);
                        }
                        uint2 pk = { pkbf2(pv[0], pv[1]), pkbf2(pv[2], pv[3]) };
                        *(uint2*)&Pl[w][nb*16 + lr][mb*16 + g*4] = pk;
                    }
                }

                for (int kb = 0; kb < kb_max; ++kb) {
                    #pragma unroll
                    for (int mv = 0; mv < 4; ++mv) {
                        bf16x8 vf = *(const bf16x8*)(Vtg +
                            ((size_t)bh*64 + mv*16 + lr)*TT + kc*64 + kb*32 + g*8);
                        #pragma unroll
                        for (int nb = 0; nb < 2; ++nb) {
                            bf16x8 pf = *(const bf16x8*)&Pl[w][nb*16 + lr][kb*32 + g*8];
                            o[mv][nb] = MFMA_BF16(vf, pf, o[mv][nb], 0, 0, 0);
                        }
                    }
                    #pragma unroll
                    for (int nb = 0; nb < 2; ++nb) {
                        bf16x8 pf = *(const bf16x8*)&Pl[w][nb*16 + lr][kb*32 + g*8];
                        dacc[nb] = MFMA_BF16(ones, pf, dacc[nb], 0, 0, 0);
                    }
                }
            }

            __syncthreads();   // waves done with Pl (scratch overlays it)

            #pragma unroll
            for (int mv = 0; mv < 4; ++mv)
                #pragma unroll
                for (int nb = 0; nb < 2; ++nb)
                    *(f32x4*)&scf[(size_t)(w*32 + nb*16 + lr)*68 + mv*16 + g*4] = o[mv][nb];
            if (g == 0) {
                scd[w*32 + lr]      = dacc[0][0];
                scd[w*32 + 16 + lr] = dacc[1][0];
            }

            __syncthreads();

            {
                const int q  = tid >> 4;           // 0..31
                const int v0 = (tid & 15) * 4;     // 0..60
                float dtot = 0.f;
                #pragma unroll
                for (int ww = 0; ww < 8; ++ww) dtot += scd[ww*32 + q];
                const float inv = 1.0f / (dtot + 1e-12f);
                float o0 = 0.f, o1 = 0.f, o2 = 0.f, o3 = 0.f;
                #pragma unroll
                for (int ww = 0; ww < 8; ++ww) {
                    const float* p = &scf[(size_t)(ww*32 + q)*68 + v0];
                    o0 += p[0]; o1 += p[1]; o2 += p[2]; o3 += p[3];
                }
                uint2 pk = { pkbf2(o0*inv, o1*inv), pkbf2(o2*inv, o3*inv) };
                *(uint2*)(Yb + ((size_t)(b*TT + qt*32 + q))*DD + h*HDIM + v0) = pk;
            }
        }
    }
    gbar(B, S, 3, xcd);

    // ---------------- phase 3: output projection 64x64 ----------------
    {
        float (*sc)[64][66] = (float(*)[64][66])smem;    // [2][64][66] 33.8KB
        const int m0 = (bid & 31) * 64, n0 = (bid >> 5) * 64;
        const int kw = w >> 2, mw = w & 1, nw = (w >> 1) & 1;

        f32x4 acc[2][2] = {};
        const ushort* Ar = Yb  + (size_t)(m0 + mw*32 + lr) * 512 + kw*256 + g*8;
        const ushort* Br = Wob + (size_t)(n0 + nw*32 + lr) * 512 + kw*256 + g*8;

        #pragma unroll
        for (int ks = 0; ks < 8; ++ks) {
            bf16x8 a0 = *(const bf16x8*)(Ar + ks*32);
            bf16x8 a1 = *(const bf16x8*)(Ar + (size_t)16*512 + ks*32);
            bf16x8 b0 = *(const bf16x8*)(Br + ks*32);
            bf16x8 b1 = *(const bf16x8*)(Br + (size_t)16*512 + ks*32);
            acc[0][0] = MFMA_BF16(a0, b0, acc[0][0], 0, 0, 0);
            acc[0][1] = MFMA_BF16(a0, b1, acc[0][1], 0, 0, 0);
            acc[1][0] = MFMA_BF16(a1, b0, acc[1][0], 0, 0, 0);
            acc[1][1] = MFMA_BF16(a1, b1, acc[1][1], 0, 0, 0);
        }

        #pragma unroll
        for (int mb = 0; mb < 2; ++mb)
            #pragma unroll
            for (int nb = 0; nb < 2; ++nb)
                #pragma unroll
                for (int r = 0; r < 4; ++r)
                    sc[kw][mw*32 + mb*16 + g*4 + r][nw*32 + nb*16 + lr] = acc[mb][nb][r];
        __syncthreads();

        const int vl = tid & 63, rg = tid >> 6;
        #pragma unroll
        for (int j = 0; j < 8; ++j) {
            const float v = sc[0][rg*8 + j][vl] + sc[1][rg*8 + j][vl];
            Out[(size_t)(m0 + rg*8 + j)*512 + n0 + vl] = v;
        }
    }
}

// ---------------------------------------------------------------------------
extern "C" void kernel_launch(void* const* d_in, const int* in_sizes, int n_in,
                              void* d_out, int out_size, void* d_ws, size_t ws_size,
                              hipStream_t stream) {
    const float* X  = (const float*)d_in[0];   // (2,1024,512)
    const float* Wq = (const float*)d_in[1];   // (128,512)
    const float* Wk = (const float*)d_in[2];   // (128,512)
    const float* Wv = (const float*)d_in[3];   // (512,512)
    const float* Wo = (const float*)d_in[4];   // (512,512)
    float* out = (float*)d_out;                // (2,1024,512)

    ushort* ws = (ushort*)d_ws;
    ushort* Xb  = ws;                    // 2048*512   = 1048576
    ushort* Wb  = Xb  + 1048576;         // 768*512    = 393216
    ushort* Wob = Wb  + 393216;          // 512*512    = 262144
    ushort* Qb  = Wob + 262144;          // 16*1024*16 = 262144
    ushort* Kb  = Qb  + 262144;          // 262144
    ushort* Vtg = Kb  + 262144;          // 16*64*1024 = 1048576
    ushort* Yb  = Vtg + 1048576;         // 2048*512   = 1048576
    unsigned long long* Bar = (unsigned long long*)(ws + 4325376); // 8-aligned
    // layout: B[0..71] ull (A, F1..F3, NX, R[x] @ B[8+8x]) | S[0..31] u32
    //         (X0 census slots + 3x8 winner slots) = 576 + 128 = 704 bytes

    // zero barrier state every call (graph-capture-legal, replay-safe)
    hipMemsetAsync((void*)Bar, 0, 704, stream);

    fused_all<<<256, 512, 0, stream>>>(X, Wq, Wk, Wv, Wo,
                                       Xb, Wb, Wob, Qb, Kb, Vtg, Yb, out, Bar);
}

// Round 20
// 60.309 us; speedup vs baseline: 5.1508x; 1.1100x over previous
//
#include <hip/hip_runtime.h>
#include <hip/hip_bf16.h>

#define BB 2
#define TT 1024
#define DD 512
#define HH 8
#define FF 16
#define HDIM 64
#define BT (BB*TT)   // 2048

typedef short bf16x8 __attribute__((ext_vector_type(8)));
typedef float f32x4  __attribute__((ext_vector_type(4)));
#define MFMA_BF16 __builtin_amdgcn_mfma_f32_16x16x32_bf16

__device__ __forceinline__ ushort f2b(float f) {
    uint u = __float_as_uint(f);
    uint r = (u + 0x7fffu + ((u >> 16) & 1u)) >> 16;
    return (ushort)r;
}

__device__ __forceinline__ uint pkbf2(float a, float b) {
    __hip_bfloat162 h = __float22bfloat162_rn(make_float2(a, b));
    union { __hip_bfloat162 h2; uint u; } c; c.h2 = h;
    return c.u;
}

__device__ __forceinline__ uint get_xcc() {
    uint x;
    asm volatile("s_getreg_b32 %0, hwreg(HW_REG_XCC_ID)" : "=s"(x));
    return x & 7u;
}

// ---------------------------------------------------------------------------
// Hierarchical grid barrier, DISTRIBUTED ARRIVAL (8 parallel per-XCD counter
// chains instead of one 256-RMW serialized line; ~45ns/same-line-RMW was the
// 12us/barrier cost in round 19).
// Memory layout in B (u64, all zeroed per call):
//   B[1..3]   = F_k : per-barrier fence-done counters
//   B[4]      = NX  : number of populated XCDs (phase-0 census)
//   B[8+8x]   = R[x]: per-XCD release epoch, 64B-spaced
//   B[80+8x]  = Ax[x]: per-XCD arrive counters, 64B-spaced (cumulative)
// S (u32): S[0..7] census slots; S[8+(k-1)*8+x] per-barrier winner slots.
// Barrier k: each block incs Ax[own-XCD]; per-XCD CAS winner polls
// sum(Ax) >= 256k (8 indep loads/iter -> one latency), reads NX,
// __threadfence (8 parallel wbl2+inv), incs F_k, polls F_k >= NX, sets
// R[x]=k; non-winners poll only R[own-XCD] (<=32 pollers/line).
// Distribution-agnostic + block-counting targets => cannot deadlock.
// ---------------------------------------------------------------------------
__device__ __forceinline__ void gbar(unsigned long long* B, uint* S,
                                     int k, uint xcd) {
    __syncthreads();                    // stores drained to local L2
    if (threadIdx.x == 0) {
        atomicAdd(&B[80 + (size_t)xcd * 8], 1ull);   // distributed arrive
        if (atomicCAS(&S[8 + (k - 1) * 8 + xcd], 0u, 1u) == 0u) {
            const unsigned long long tA = 256ull * (unsigned long long)k;
            for (;;) {
                unsigned long long ssum = 0;
                #pragma unroll
                for (int x = 0; x < 8; ++x)
                    ssum += __hip_atomic_load(&B[80 + (size_t)x * 8],
                                              __ATOMIC_RELAXED,
                                              __HIP_MEMORY_SCOPE_SYSTEM);
                if (ssum >= tA) break;
                __builtin_amdgcn_s_sleep(2);
            }
            const unsigned long long NX =
                __hip_atomic_load(&B[4], __ATOMIC_RELAXED,
                                  __HIP_MEMORY_SCOPE_SYSTEM);
            __threadfence();            // one wbl2+inv per XCD, in parallel
            atomicAdd(&B[k], 1ull);
            while (__hip_atomic_load(&B[k], __ATOMIC_RELAXED,
                                     __HIP_MEMORY_SCOPE_SYSTEM) < NX)
                __builtin_amdgcn_s_sleep(2);
            __hip_atomic_store(&B[8 + (size_t)xcd * 8],
                               (unsigned long long)k,
                               __ATOMIC_RELAXED, __HIP_MEMORY_SCOPE_SYSTEM);
        }
        while (__hip_atomic_load(&B[8 + (size_t)xcd * 8], __ATOMIC_RELAXED,
                                 __HIP_MEMORY_SCOPE_SYSTEM)
               < (unsigned long long)k)
            __builtin_amdgcn_s_sleep(2);
    }
    __syncthreads();
}

// ---------------------------------------------------------------------------
// One persistent kernel, 256 blocks x 512 threads, 4 phases / 3 barriers.
// Phase bodies byte-identical to round 19 (numerically verified).
// ---------------------------------------------------------------------------
__global__ __launch_bounds__(512) void fused_all(
    const float* __restrict__ X,  const float* __restrict__ Wq,
    const float* __restrict__ Wk, const float* __restrict__ Wv,
    const float* __restrict__ Wo,
    ushort* __restrict__ Xb, ushort* __restrict__ Wb, ushort* __restrict__ Wob,
    ushort* __restrict__ Qb, ushort* __restrict__ Kb, ushort* __restrict__ Vtg,
    ushort* __restrict__ Yb, float* __restrict__ Out,
    unsigned long long* __restrict__ Bar)
{
    __shared__ float smem[17664];   // 70656 B, aliased per phase

    unsigned long long* B = Bar;
    uint* S = (uint*)(Bar + 144);

    const int bid = blockIdx.x;
    const int tid = threadIdx.x, w = tid >> 6, l = tid & 63;
    const int lr = l & 15, g = l >> 4;
    const uint xcd = get_xcc();

    // phase-0 preamble: XCD census (NX final before any barrier-1 winner
    // reads it -- the asm use forces the NX-inc to complete before this
    // thread's later arrive-inc is issued).
    if (tid == 0) {
        if (atomicCAS(&S[xcd], 0u, 1u) == 0u) {
            unsigned long long r = atomicAdd(&B[4], 1ull);
            asm volatile("" :: "v"((uint)r));
        }
    }

    // ---------------- phase 0: cast ----------------
    {
        const int gtid = bid * 512 + tid;              // 0..131071
        for (int u = gtid; u < 425984; u += 131072) {
            const int i4 = u * 4;
            const float* src; ushort* dst;
            if (i4 < 1048576)      { src = X  + i4;             dst = Xb + i4; }
            else if (i4 < 1114112) { src = Wq + (i4 - 1048576); dst = Wb + (i4 - 1048576); }
            else if (i4 < 1179648) { src = Wk + (i4 - 1114112); dst = Wb + 65536 + (i4 - 1114112); }
            else if (i4 < 1441792) { src = Wv + (i4 - 1179648); dst = Wb + 131072 + (i4 - 1179648); }
            else                   { src = Wo + (i4 - 1441792); dst = Wob + (i4 - 1441792); }
            float4 v = *(const float4*)src;
            ushort4 o = { f2b(v.x), f2b(v.y), f2b(v.z), f2b(v.w) };
            *(ushort4*)dst = o;
        }
    }
    gbar(B, S, 1, xcd);

    // ---------------- phase 1: QKV gemm 64x96 ----------------
    {
        float (*sc)[64][100] = (float(*)[64][100])smem;   // [2][64][100] 51.2KB
        const int m0 = (bid & 31) * 64, n0 = (bid >> 5) * 96;
        const int kw = w >> 2, mw = w & 1, nw = (w >> 1) & 1;

        f32x4 acc[2][3] = {};
        const ushort* Ar = Xb + (size_t)(m0 + mw*32 + lr) * 512 + kw*256 + g*8;
        const ushort* Br = Wb + (size_t)(n0 + nw*48 + lr) * 512 + kw*256 + g*8;

        #pragma unroll
        for (int ks = 0; ks < 8; ++ks) {
            bf16x8 a0 = *(const bf16x8*)(Ar + ks*32);
            bf16x8 a1 = *(const bf16x8*)(Ar + (size_t)16*512 + ks*32);
            bf16x8 b0 = *(const bf16x8*)(Br + ks*32);
            bf16x8 b1 = *(const bf16x8*)(Br + (size_t)16*512 + ks*32);
            bf16x8 b2 = *(const bf16x8*)(Br + (size_t)32*512 + ks*32);
            acc[0][0] = MFMA_BF16(a0, b0, acc[0][0], 0, 0, 0);
            acc[0][1] = MFMA_BF16(a0, b1, acc[0][1], 0, 0, 0);
            acc[0][2] = MFMA_BF16(a0, b2, acc[0][2], 0, 0, 0);
            acc[1][0] = MFMA_BF16(a1, b0, acc[1][0], 0, 0, 0);
            acc[1][1] = MFMA_BF16(a1, b1, acc[1][1], 0, 0, 0);
            acc[1][2] = MFMA_BF16(a1, b2, acc[1][2], 0, 0, 0);
        }

        #pragma unroll
        for (int mb = 0; mb < 2; ++mb)
            #pragma unroll
            for (int nb = 0; nb < 3; ++nb)
                #pragma unroll
                for (int r = 0; r < 4; ++r)
                    sc[kw][mw*32 + mb*16 + g*4 + r][nw*48 + nb*16 + lr] = acc[mb][nb][r];
        __syncthreads();

        if (tid < 384) {
            const int col = tid % 96;
            const int rg4 = tid / 96;            // 0..3 -> rows rg4*16..+15
            const int cg  = n0 + col;
            const int tok0 = (bid & 31) * 64 + rg4*16;
            const int b = tok0 >> 10, tt0 = tok0 & 1023;
            float v16[16];
            #pragma unroll
            for (int j = 0; j < 16; ++j)
                v16[j] = sc[0][rg4*16 + j][col] + sc[1][rg4*16 + j][col];
            if (cg < 256) {
                const bool isQ = cg < 128;
                const int c = isQ ? cg : cg - 128;
                const int h = c >> 4, f = c & 15;
                ushort* Dst = isQ ? Qb : Kb;
                const float scale = isQ ? 1.0f : 0.25f;   // K pre-scaled 1/4
                #pragma unroll
                for (int j = 0; j < 16; ++j)
                    Dst[((size_t)(b*HH + h)*TT + tt0 + j)*FF + f] = f2b(v16[j] * scale);
            } else {
                const int c = cg - 256;
                const int h = c >> 6, vch = c & 63;
                ushort us[16];
                #pragma unroll
                for (int j = 0; j < 16; ++j) us[j] = f2b(v16[j]);
                ushort* base = Vtg + ((size_t)(b*HH + h)*64 + vch)*TT + tt0;
                *(uint4*)(base)     = *(uint4*)&us[0];
                *(uint4*)(base + 8) = *(uint4*)&us[8];
            }
        }
    }
    gbar(B, S, 2, xcd);

    // ---------------- phase 2: attention (2 LPT-paired units) ----------------
    {
        short (*Pl)[32][72] = (short(*)[32][72])smem;    // bf16 P [8][32][72]
        float* scf = smem;                               // epi overlay [8][32][68]
        float* scd = smem + 8*32*68;                     // epi [8][32]
        const bf16x8 zf = {0,0,0,0,0,0,0,0};
        const bf16x8 ones = {16256,16256,16256,16256,16256,16256,16256,16256};

        #pragma unroll 1
        for (int ui = 0; ui < 2; ++ui) {
            const int u = ui ? (511 - bid) : bid;
            const int qt = 31 - (u >> 4);
            const int bh = u & 15;
            const int b = bh >> 3, h = bh & 7;
            const int qend = qt*32 + 32;
            const int nkc = (qt + 2) >> 1;

            __syncthreads();   // protect LDS overlay across units

            bf16x8 qf[2];
            #pragma unroll
            for (int nb = 0; nb < 2; ++nb)
                qf[nb] = (l < 32)
                    ? *(const bf16x8*)(Qb + ((size_t)bh*TT + qt*32 + nb*16 + lr)*FF + g*8)
                    : zf;

            f32x4 o[4][2] = {};
            f32x4 dacc[2] = {};

            for (int kc = w; kc < nkc; kc += 8) {
                const bool diagc = (kc == nkc - 1);
                const int act = qend - kc*64;
                const int nmb = diagc ? (act >> 4) : 4;   // 2 or 4
                const int kb_max = nmb >> 1;

                for (int mb = 0; mb < nmb; ++mb) {
                    bf16x8 kf = (l < 32)
                        ? *(const bf16x8*)(Kb + ((size_t)bh*TT + kc*64 + mb*16 + lr)*FF + g*8)
                        : zf;
                    #pragma unroll
                    for (int nb = 0; nb < 2; ++nb) {
                        f32x4 z4 = {};
                        f32x4 s = MFMA_BF16(kf, qf[nb], z4, 0, 0, 0);
                        float pv[4];
                        if (diagc) {
                            const int qg = qt*32 + nb*16 + lr;
                            const int kg0 = kc*64 + mb*16 + g*4;
                            #pragma unroll
                            for (int r = 0; r < 4; ++r) {
                                float pp = fmaf(s[r], fmaf(s[r], 0.5f, 1.0f), 1.0f);
                                pv[r] = (kg0 + r > qg) ? 0.f : pp;
                            }
                        } else {
                            #pragma unroll
                            for (int r = 0; r < 4; ++r)
                                pv[r] = fmaf(s[r], fmaf(s[r], 0.5f, 1.0f), 1.0f);
                        }
                        uint2 pk = { pkbf2(pv[0], pv[1]), pkbf2(pv[2], pv[3]) };
                        *(uint2*)&Pl[w][nb*16 + lr][mb*16 + g*4] = pk;
                    }
                }

                for (int kb = 0; kb < kb_max; ++kb) {
                    #pragma unroll
                    for (int mv = 0; mv < 4; ++mv) {
                        bf16x8 vf = *(const bf16x8*)(Vtg +
                            ((size_t)bh*64 + mv*16 + lr)*TT + kc*64 + kb*32 + g*8);
                        #pragma unroll
                        for (int nb = 0; nb < 2; ++nb) {
                            bf16x8 pf = *(const bf16x8*)&Pl[w][nb*16 + lr][kb*32 + g*8];
                            o[mv][nb] = MFMA_BF16(vf, pf, o[mv][nb], 0, 0, 0);
                        }
                    }
                    #pragma unroll
                    for (int nb = 0; nb < 2; ++nb) {
                        bf16x8 pf = *(const bf16x8*)&Pl[w][nb*16 + lr][kb*32 + g*8];
                        dacc[nb] = MFMA_BF16(ones, pf, dacc[nb], 0, 0, 0);
                    }
                }
            }

            __syncthreads();   // waves done with Pl (scratch overlays it)

            #pragma unroll
            for (int mv = 0; mv < 4; ++mv)
                #pragma unroll
                for (int nb = 0; nb < 2; ++nb)
                    *(f32x4*)&scf[(size_t)(w*32 + nb*16 + lr)*68 + mv*16 + g*4] = o[mv][nb];
            if (g == 0) {
                scd[w*32 + lr]      = dacc[0][0];
                scd[w*32 + 16 + lr] = dacc[1][0];
            }

            __syncthreads();

            {
                const int q  = tid >> 4;           // 0..31
                const int v0 = (tid & 15) * 4;     // 0..60
                float dtot = 0.f;
                #pragma unroll
                for (int ww = 0; ww < 8; ++ww) dtot += scd[ww*32 + q];
                const float inv = 1.0f / (dtot + 1e-12f);
                float o0 = 0.f, o1 = 0.f, o2 = 0.f, o3 = 0.f;
                #pragma unroll
                for (int ww = 0; ww < 8; ++ww) {
                    const float* p = &scf[(size_t)(ww*32 + q)*68 + v0];
                    o0 += p[0]; o1 += p[1]; o2 += p[2]; o3 += p[3];
                }
                uint2 pk = { pkbf2(o0*inv, o1*inv), pkbf2(o2*inv, o3*inv) };
                *(uint2*)(Yb + ((size_t)(b*TT + qt*32 + q))*DD + h*HDIM + v0) = pk;
            }
        }
    }
    gbar(B, S, 3, xcd);

    // ---------------- phase 3: output projection 64x64 ----------------
    {
        float (*sc)[64][66] = (float(*)[64][66])smem;    // [2][64][66] 33.8KB
        const int m0 = (bid & 31) * 64, n0 = (bid >> 5) * 64;
        const int kw = w >> 2, mw = w & 1, nw = (w >> 1) & 1;

        f32x4 acc[2][2] = {};
        const ushort* Ar = Yb  + (size_t)(m0 + mw*32 + lr) * 512 + kw*256 + g*8;
        const ushort* Br = Wob + (size_t)(n0 + nw*32 + lr) * 512 + kw*256 + g*8;

        #pragma unroll
        for (int ks = 0; ks < 8; ++ks) {
            bf16x8 a0 = *(const bf16x8*)(Ar + ks*32);
            bf16x8 a1 = *(const bf16x8*)(Ar + (size_t)16*512 + ks*32);
            bf16x8 b0 = *(const bf16x8*)(Br + ks*32);
            bf16x8 b1 = *(const bf16x8*)(Br + (size_t)16*512 + ks*32);
            acc[0][0] = MFMA_BF16(a0, b0, acc[0][0], 0, 0, 0);
            acc[0][1] = MFMA_BF16(a0, b1, acc[0][1], 0, 0, 0);
            acc[1][0] = MFMA_BF16(a1, b0, acc[1][0], 0, 0, 0);
            acc[1][1] = MFMA_BF16(a1, b1, acc[1][1], 0, 0, 0);
        }

        #pragma unroll
        for (int mb = 0; mb < 2; ++mb)
            #pragma unroll
            for (int nb = 0; nb < 2; ++nb)
                #pragma unroll
                for (int r = 0; r < 4; ++r)
                    sc[kw][mw*32 + mb*16 + g*4 + r][nw*32 + nb*16 + lr] = acc[mb][nb][r];
        __syncthreads();

        const int vl = tid & 63, rg = tid >> 6;
        #pragma unroll
        for (int j = 0; j < 8; ++j) {
            const float v = sc[0][rg*8 + j][vl] + sc[1][rg*8 + j][vl];
            Out[(size_t)(m0 + rg*8 + j)*512 + n0 + vl] = v;
        }
    }
}

// ---------------------------------------------------------------------------
extern "C" void kernel_launch(void* const* d_in, const int* in_sizes, int n_in,
                              void* d_out, int out_size, void* d_ws, size_t ws_size,
                              hipStream_t stream) {
    const float* X  = (const float*)d_in[0];   // (2,1024,512)
    const float* Wq = (const float*)d_in[1];   // (128,512)
    const float* Wk = (const float*)d_in[2];   // (128,512)
    const float* Wv = (const float*)d_in[3];   // (512,512)
    const float* Wo = (const float*)d_in[4];   // (512,512)
    float* out = (float*)d_out;                // (2,1024,512)

    ushort* ws = (ushort*)d_ws;
    ushort* Xb  = ws;                    // 2048*512   = 1048576
    ushort* Wb  = Xb  + 1048576;         // 768*512    = 393216
    ushort* Wob = Wb  + 393216;          // 512*512    = 262144
    ushort* Qb  = Wob + 262144;          // 16*1024*16 = 262144
    ushort* Kb  = Qb  + 262144;          // 262144
    ushort* Vtg = Kb  + 262144;          // 16*64*1024 = 1048576
    ushort* Yb  = Vtg + 1048576;         // 2048*512   = 1048576
    unsigned long long* Bar = (unsigned long long*)(ws + 4325376); // 8-aligned
    // layout: B[0..143] u64 (F1..F3 @1..3, NX @4, R[x] @8+8x, Ax[x] @80+8x)
    //         | S[0..31] u32 (census + 3x8 winner slots) = 1152 + 128 = 1280 B

    // zero barrier state every call (graph-capture-legal, replay-safe)
    hipMemsetAsync((void*)Bar, 0, 1280, stream);

    fused_all<<<256, 512, 0, stream>>>(X, Wq, Wk, Wv, Wo,
                                       Xb, Wb, Wob, Qb, Kb, Vtg, Yb, out, Bar);
}

// Round 21
// 48.190 us; speedup vs baseline: 6.4461x; 1.2515x over previous
//
#include <hip/hip_runtime.h>
#include <hip/hip_bf16.h>

#define BB 2
#define TT 1024
#define DD 512
#define HH 8
#define FF 16
#define HDIM 64
#define BT (BB*TT)   // 2048

typedef short bf16x8 __attribute__((ext_vector_type(8)));
typedef float f32x4  __attribute__((ext_vector_type(4)));
#define MFMA_BF16 __builtin_amdgcn_mfma_f32_16x16x32_bf16

// float -> bf16 round-to-nearest-even (scalar)
__device__ __forceinline__ ushort f2b(float f) {
    uint u = __float_as_uint(f);
    uint r = (u + 0x7fffu + ((u >> 16) & 1u)) >> 16;
    return (ushort)r;
}

// pack two floats -> one dword of 2 bf16
__device__ __forceinline__ uint pkbf2(float a, float b) {
    __hip_bfloat162 h = __float22bfloat162_rn(make_float2(a, b));
    union { __hip_bfloat162 h2; uint u; } c; c.h2 = h;
    return c.u;
}

// ---------------------------------------------------------------------------
// Kernel 0: cast inputs to bf16 (round-14 structure, unchanged).
// ---------------------------------------------------------------------------
__global__ __launch_bounds__(256) void cast_all(
    const float* __restrict__ X,  const float* __restrict__ Wq,
    const float* __restrict__ Wk, const float* __restrict__ Wv,
    const float* __restrict__ Wo,
    ushort* __restrict__ Xb, ushort* __restrict__ Wb, ushort* __restrict__ Wob)
{
    const int i4 = (blockIdx.x * 256 + threadIdx.x) * 4;
    const float* src; ushort* dst;
    if (i4 < 1048576)      { src = X  + i4;             dst = Xb + i4; }
    else if (i4 < 1114112) { src = Wq + (i4 - 1048576); dst = Wb + (i4 - 1048576); }
    else if (i4 < 1179648) { src = Wk + (i4 - 1114112); dst = Wb + 65536 + (i4 - 1114112); }
    else if (i4 < 1441792) { src = Wv + (i4 - 1179648); dst = Wb + 131072 + (i4 - 1179648); }
    else                   { src = Wo + (i4 - 1441792); dst = Wob + (i4 - 1441792); }
    float4 v = *(const float4*)src;
    ushort4 o = { f2b(v.x), f2b(v.y), f2b(v.z), f2b(v.w) };
    *(ushort4*)dst = o;
}

// ---------------------------------------------------------------------------
// Kernel 1: QKV projection, bf16 MFMA, K-split 8-wave (round-14 compute).
// K output pre-scaled by 0.25 (exact pow2).
// NEW: fully-coalesced epilogue.
//   Q/K tiles (n0<256): 512 thr = 4 head-groups x 128; thread = one uint4
//     (8 f's, half a token row); 128 threads = 64 tokens = 2KB contiguous.
//   V tiles: 512 thr = 64 vch-rows x 8; thread = one uint4 (8 tokens);
//     8 threads = 128B contiguous per Vt row.
// ---------------------------------------------------------------------------
__global__ __launch_bounds__(512) void qkv_mfma(
    const ushort* __restrict__ Xb, const ushort* __restrict__ Wb,
    ushort* __restrict__ Qb, ushort* __restrict__ Kb, ushort* __restrict__ Vtg)
{
    __shared__ float sc[2][64][66];
    const int m0 = blockIdx.x * 64, n0 = blockIdx.y * 64;
    const int tid = threadIdx.x, w = tid >> 6, l = tid & 63;
    const int kw = w >> 2, mw = w & 1, nw = (w >> 1) & 1;
    const int lr = l & 15, g = l >> 4;

    f32x4 acc[2][2] = {};
    const ushort* Ar = Xb + (size_t)(m0 + mw*32 + lr) * 512 + kw*256 + g*8;
    const ushort* Br = Wb + (size_t)(n0 + nw*32 + lr) * 512 + kw*256 + g*8;

    bf16x8 a0c = *(const bf16x8*)(Ar);
    bf16x8 a1c = *(const bf16x8*)(Ar + (size_t)16*512);
    bf16x8 b0c = *(const bf16x8*)(Br);
    bf16x8 b1c = *(const bf16x8*)(Br + (size_t)16*512);
    #pragma unroll
    for (int ks = 0; ks < 8; ++ks) {
        bf16x8 a0n = a0c, a1n = a1c, b0n = b0c, b1n = b1c;
        if (ks < 7) {
            a0n = *(const bf16x8*)(Ar + (ks+1)*32);
            a1n = *(const bf16x8*)(Ar + (size_t)16*512 + (ks+1)*32);
            b0n = *(const bf16x8*)(Br + (ks+1)*32);
            b1n = *(const bf16x8*)(Br + (size_t)16*512 + (ks+1)*32);
        }
        acc[0][0] = MFMA_BF16(a0c, b0c, acc[0][0], 0, 0, 0);
        acc[0][1] = MFMA_BF16(a0c, b1c, acc[0][1], 0, 0, 0);
        acc[1][0] = MFMA_BF16(a1c, b0c, acc[1][0], 0, 0, 0);
        acc[1][1] = MFMA_BF16(a1c, b1c, acc[1][1], 0, 0, 0);
        a0c = a0n; a1c = a1n; b0c = b0n; b1c = b1n;
    }

    #pragma unroll
    for (int mb = 0; mb < 2; ++mb)
        #pragma unroll
        for (int nb = 0; nb < 2; ++nb)
            #pragma unroll
            for (int r = 0; r < 4; ++r)
                sc[kw][mw*32 + mb*16 + g*4 + r][nw*32 + nb*16 + lr] = acc[mb][nb][r];
    __syncthreads();

    if (n0 < 256) {
        // Q/K tile: 4 head-groups of 16 features each.
        const int hq   = tid >> 7;           // 0..3 head-group in tile
        const int r    = tid & 127;
        const int m    = r >> 1;             // 0..63 local token
        const int half = r & 1;              // 0/1: features half*8..+8
        const int c0 = n0 + hq*16;
        const bool isQ = c0 < 128;
        const int c = isQ ? c0 : c0 - 128;
        const int h = c >> 4;
        ushort* Dst = isQ ? Qb : Kb;
        const float scale = isQ ? 1.0f : 0.25f;   // K pre-scaled 1/4
        const int tok0 = m0 + m;
        const int b = tok0 >> 10, tt = tok0 & 1023;
        const int cb = hq*16 + half*8;
        ushort us[8];
        #pragma unroll
        for (int j = 0; j < 8; ++j)
            us[j] = f2b((sc[0][m][cb + j] + sc[1][m][cb + j]) * scale);
        *(uint4*)&Dst[((size_t)(b*HH + h)*TT + tt)*FF + half*8] = *(uint4*)us;
    } else {
        // V tile: single head, 64 vch rows x 64 tokens (transposed store).
        const int h   = (n0 - 256) >> 6;
        const int row = tid >> 3;            // 0..63 vch
        const int tc  = tid & 7;             // token chunk: tokens tc*8..+8
        const int tok0 = m0 + tc*8;
        const int b = tok0 >> 10, tt0 = tok0 & 1023;
        ushort us[8];
        #pragma unroll
        for (int j = 0; j < 8; ++j)
            us[j] = f2b(sc[0][tc*8 + j][row] + sc[1][tc*8 + j][row]);
        *(uint4*)&Vtg[((size_t)(b*HH + h)*64 + row)*TT + tt0] = *(uint4*)us;
    }
}

// ---------------------------------------------------------------------------
// Kernel 2: causal Taylor attention, bf16 MFMA, 8-wave split-K (round-14,
// unchanged): 32 q-rows/block, 512 blocks, VALU diet + den-MFMA.
// ---------------------------------------------------------------------------
__global__ __launch_bounds__(512) void attn_mfma(
    const ushort* __restrict__ Qb, const ushort* __restrict__ Kb,
    const ushort* __restrict__ Vtg, ushort* __restrict__ Yb)
{
    __shared__ float smem[8*32*68 + 8*32];           // 70656 B
    short (*Pl)[32][72] = (short(*)[32][72])smem;    // [wave][q32][k64+8]
    float* scf = smem;                               // epi: [8][32][68]
    float* scd = smem + 8*32*68;                     // epi: [8][32]

    const int bid = blockIdx.x;
    const int qt = 31 - (bid >> 4);       // heavy q-tiles dispatch first (LPT)
    const int bh = bid & 15;
    const int b = bh >> 3, h = bh & 7;
    const int tid = threadIdx.x, w = tid >> 6, l = tid & 63;
    const int lr = l & 15, g = l >> 4;
    const int qend = qt*32 + 32;
    const int nkc = (qt + 2) >> 1;        // ceil(qend/64)
    const bf16x8 zf = {0,0,0,0,0,0,0,0};
    const bf16x8 ones = {16256,16256,16256,16256,16256,16256,16256,16256}; // bf16 1.0

    bf16x8 qf[2];
    #pragma unroll
    for (int nb = 0; nb < 2; ++nb)
        qf[nb] = (l < 32)
            ? *(const bf16x8*)(Qb + ((size_t)bh*TT + qt*32 + nb*16 + lr)*FF + g*8)
            : zf;

    f32x4 o[4][2] = {};       // o[mv][nb]: O^T partial over this wave's kc set
    f32x4 dacc[2] = {};       // den[q=lr] per nb (replicated across regs)

    for (int kc = w; kc < nkc; kc += 8) {
        const bool diagc = (kc == nkc - 1);           // wave-uniform
        const int act = qend - kc*64;                 // 32 or 64 on diag, else 64
        const int nmb = diagc ? (act >> 4) : 4;       // 2 or 4 (always even)
        const int kb_max = nmb >> 1;                  // 1 or 2

        // QK^T (swapped), cheap poly, diag-only mask, pack -> P
        for (int mb = 0; mb < nmb; ++mb) {
            bf16x8 kf = (l < 32)
                ? *(const bf16x8*)(Kb + ((size_t)bh*TT + kc*64 + mb*16 + lr)*FF + g*8)
                : zf;
            #pragma unroll
            for (int nb = 0; nb < 2; ++nb) {
                f32x4 z4 = {};
                f32x4 s = MFMA_BF16(kf, qf[nb], z4, 0, 0, 0);  // s pre-scaled
                float pv[4];
                if (diagc) {
                    const int qg = qt*32 + nb*16 + lr;
                    const int kg0 = kc*64 + mb*16 + g*4;
                    #pragma unroll
                    for (int r = 0; r < 4; ++r) {
                        float pp = fmaf(s[r], fmaf(s[r], 0.5f, 1.0f), 1.0f);
                        pv[r] = (kg0 + r > qg) ? 0.f : pp;
                    }
                } else {
                    #pragma unroll
                    for (int r = 0; r < 4; ++r)
                        pv[r] = fmaf(s[r], fmaf(s[r], 0.5f, 1.0f), 1.0f);
                }
                uint2 pk = { pkbf2(pv[0], pv[1]), pkbf2(pv[2], pv[3]) };
                *(uint2*)&Pl[w][nb*16 + lr][mb*16 + g*4] = pk;
            }
        }

        // PV + den:  O^T += V^T . P ;  den += ones . P
        for (int kb = 0; kb < kb_max; ++kb) {
            #pragma unroll
            for (int mv = 0; mv < 4; ++mv) {
                bf16x8 vf = *(const bf16x8*)(Vtg +
                    ((size_t)bh*64 + mv*16 + lr)*TT + kc*64 + kb*32 + g*8);
                #pragma unroll
                for (int nb = 0; nb < 2; ++nb) {
                    bf16x8 pf = *(const bf16x8*)&Pl[w][nb*16 + lr][kb*32 + g*8];
                    o[mv][nb] = MFMA_BF16(vf, pf, o[mv][nb], 0, 0, 0);
                }
            }
            #pragma unroll
            for (int nb = 0; nb < 2; ++nb) {
                bf16x8 pf = *(const bf16x8*)&Pl[w][nb*16 + lr][kb*32 + g*8];
                dacc[nb] = MFMA_BF16(ones, pf, dacc[nb], 0, 0, 0);
            }
        }
    }

    __syncthreads();   // all waves done with Pl (scratch overlays it)

    #pragma unroll
    for (int mv = 0; mv < 4; ++mv)
        #pragma unroll
        for (int nb = 0; nb < 2; ++nb)
            *(f32x4*)&scf[(size_t)(w*32 + nb*16 + lr)*68 + mv*16 + g*4] = o[mv][nb];
    if (g == 0) {      // lanes l<16: dacc[nb][0] holds den for q=lr
        scd[w*32 + lr]      = dacc[0][0];
        scd[w*32 + 16 + lr] = dacc[1][0];
    }

    __syncthreads();

    // combine 8 wave-partials, normalize, store bf16 Y (8B/thread coalesced)
    {
        const int q  = tid >> 4;           // 0..31
        const int v0 = (tid & 15) * 4;     // 0..60
        float dtot = 0.f;
        #pragma unroll
        for (int ww = 0; ww < 8; ++ww) dtot += scd[ww*32 + q];
        const float inv = 1.0f / (dtot + 1e-12f);
        float o0 = 0.f, o1 = 0.f, o2 = 0.f, o3 = 0.f;
        #pragma unroll
        for (int ww = 0; ww < 8; ++ww) {
            const float* p = &scf[(size_t)(ww*32 + q)*68 + v0];
            o0 += p[0]; o1 += p[1]; o2 += p[2]; o3 += p[3];
        }
        uint2 pk = { pkbf2(o0*inv, o1*inv), pkbf2(o2*inv, o3*inv) };
        *(uint2*)(Yb + ((size_t)(b*TT + qt*32 + q))*DD + h*HDIM + v0) = pk;
    }
}

// ---------------------------------------------------------------------------
// Kernel 3: output projection, bf16 MFMA, K-split 8-wave (round-14,
// unchanged).
// ---------------------------------------------------------------------------
__global__ __launch_bounds__(512) void out_mfma(
    const ushort* __restrict__ Yb, const ushort* __restrict__ Wob,
    float* __restrict__ Out)
{
    __shared__ float sc[2][64][66];
    const int m0 = blockIdx.x * 64, n0 = blockIdx.y * 64;
    const int tid = threadIdx.x, w = tid >> 6, l = tid & 63;
    const int kw = w >> 2, mw = w & 1, nw = (w >> 1) & 1;
    const int lr = l & 15, g = l >> 4;

    f32x4 acc[2][2] = {};
    const ushort* Ar = Yb  + (size_t)(m0 + mw*32 + lr) * 512 + kw*256 + g*8;
    const ushort* Br = Wob + (size_t)(n0 + nw*32 + lr) * 512 + kw*256 + g*8;

    bf16x8 a0c = *(const bf16x8*)(Ar);
    bf16x8 a1c = *(const bf16x8*)(Ar + (size_t)16*512);
    bf16x8 b0c = *(const bf16x8*)(Br);
    bf16x8 b1c = *(const bf16x8*)(Br + (size_t)16*512);
    #pragma unroll
    for (int ks = 0; ks < 8; ++ks) {
        bf16x8 a0n = a0c, a1n = a1c, b0n = b0c, b1n = b1c;
        if (ks < 7) {
            a0n = *(const bf16x8*)(Ar + (ks+1)*32);
            a1n = *(const bf16x8*)(Ar + (size_t)16*512 + (ks+1)*32);
            b0n = *(const bf16x8*)(Br + (ks+1)*32);
            b1n = *(const bf16x8*)(Br + (size_t)16*512 + (ks+1)*32);
        }
        acc[0][0] = MFMA_BF16(a0c, b0c, acc[0][0], 0, 0, 0);
        acc[0][1] = MFMA_BF16(a0c, b1c, acc[0][1], 0, 0, 0);
        acc[1][0] = MFMA_BF16(a1c, b0c, acc[1][0], 0, 0, 0);
        acc[1][1] = MFMA_BF16(a1c, b1c, acc[1][1], 0, 0, 0);
        a0c = a0n; a1c = a1n; b0c = b0n; b1c = b1n;
    }

    #pragma unroll
    for (int mb = 0; mb < 2; ++mb)
        #pragma unroll
        for (int nb = 0; nb < 2; ++nb)
            #pragma unroll
            for (int r = 0; r < 4; ++r)
                sc[kw][mw*32 + mb*16 + g*4 + r][nw*32 + nb*16 + lr] = acc[mb][nb][r];
    __syncthreads();

    const int vl = tid & 63, rg = tid >> 6;
    #pragma unroll
    for (int j = 0; j < 8; ++j) {
        const float v = sc[0][rg*8 + j][vl] + sc[1][rg*8 + j][vl];
        Out[(size_t)(m0 + rg*8 + j)*512 + n0 + vl] = v;
    }
}

// ---------------------------------------------------------------------------
extern "C" void kernel_launch(void* const* d_in, const int* in_sizes, int n_in,
                              void* d_out, int out_size, void* d_ws, size_t ws_size,
                              hipStream_t stream) {
    const float* X  = (const float*)d_in[0];   // (2,1024,512)
    const float* Wq = (const float*)d_in[1];   // (128,512)
    const float* Wk = (const float*)d_in[2];   // (128,512)
    const float* Wv = (const float*)d_in[3];   // (512,512)
    const float* Wo = (const float*)d_in[4];   // (512,512)
    float* out = (float*)d_out;                // (2,1024,512)

    ushort* ws = (ushort*)d_ws;
    ushort* Xb  = ws;                    // 2048*512   = 1048576
    ushort* Wb  = Xb  + 1048576;         // 768*512    = 393216
    ushort* Wob = Wb  + 393216;          // 512*512    = 262144
    ushort* Qb  = Wob + 262144;          // 16*1024*16 = 262144
    ushort* Kb  = Qb  + 262144;          // 262144
    ushort* Vtg = Kb  + 262144;          // 16*64*1024 = 1048576
    ushort* Yb  = Vtg + 1048576;         // 2048*512   = 1048576

    cast_all<<<1664, 256, 0, stream>>>(X, Wq, Wk, Wv, Wo, Xb, Wb, Wob);

    dim3 g1(BT/64, 768/64);   // 32 x 12 = 384 blocks, 512 thr
    qkv_mfma<<<g1, 512, 0, stream>>>(Xb, Wb, Qb, Kb, Vtg);

    attn_mfma<<<512, 512, 0, stream>>>(Qb, Kb, Vtg, Yb);

    dim3 g3(BT/64, DD/64);    // 32 x 8 = 256 blocks, 512 thr
    out_mfma<<<g3, 512, 0, stream>>>(Yb, Wob, out);
}